// Round 1
// baseline (1290.076 us; speedup 1.0000x reference)
//
#include <hip/hip_runtime.h>
#include <stdint.h>

typedef __bf16 bf16;
typedef __attribute__((ext_vector_type(8))) __bf16 bf16x8;
typedef __attribute__((ext_vector_type(4))) float f32x4;

namespace {

constexpr int cB = 4, cT = 4096, cD = 2048, cK = 1024, cH = 16, cKVH = 4, cHD = 128, cFF = 8192;
constexpr int cM = cB * cK;                 // 4096 gathered rows
constexpr int QKVW = cH * cHD + 2 * cKVH * cHD; // 3072

__device__ __forceinline__ void load_lds16(const void* g, void* l) {
  __builtin_amdgcn_global_load_lds((const __attribute__((address_space(1))) void*)g,
                                   (__attribute__((address_space(3))) void*)l, 16, 0, 0);
}

// ---------------- block reduce (256 threads = 4 waves) ----------------
template <int OP>  // 0 = sum, 1 = max
__device__ __forceinline__ float blk_reduce(float v) {
  __shared__ float sm[5];
  const int tid = threadIdx.x, lane = tid & 63, wid = tid >> 6;
#pragma unroll
  for (int o = 32; o; o >>= 1) {
    float o2 = __shfl_down(v, o, 64);
    v = OP ? fmaxf(v, o2) : v + o2;
  }
  if (lane == 0) sm[wid] = v;
  __syncthreads();
  if (tid == 0) {
    float r = sm[0];
#pragma unroll
    for (int i = 1; i < 4; ++i) r = OP ? fmaxf(r, sm[i]) : r + sm[i];
    sm[4] = r;
  }
  __syncthreads();
  float r = sm[4];
  __syncthreads();
  return r;
}

// ------------- generic 128x128 (BK=32) bf16 MFMA GEMM: C = A * B^T -------------
// A: MxKd row-major (lda), B: NxKd row-major (ldb, i.e. pre-transposed weights)
template <class Epi, bool KLIMIT>
__device__ __forceinline__ void gemm_core(const bf16* __restrict__ A, int lda,
                                          const bf16* __restrict__ Bm, int ldb,
                                          int Kd, const Epi& epi) {
  __shared__ __align__(16) bf16 sA[128 * 32];
  __shared__ __align__(16) bf16 sB[128 * 32];
  const int tid = threadIdx.x;
  const int lane = tid & 63;
  const int wid = tid >> 6;
  const int wr = wid >> 1, wc = wid & 1;
  const int bm = blockIdx.y, bn = blockIdx.x;
  const int l15 = lane & 15;
  const int kh = (lane >> 4) * 8;

  f32x4 acc[4][4] = {};
  int ktiles = Kd >> 5;
  if (KLIMIT) {
    int lim = ((bm + 1) * 128) >> 5;
    if (lim < ktiles) ktiles = lim;
  }
  const bf16* Abase = A + (int64_t)bm * 128 * lda;
  const bf16* Bbase = Bm + (int64_t)bn * 128 * ldb;

  for (int kt = 0; kt < ktiles; ++kt) {
#pragma unroll
    for (int i = 0; i < 2; ++i) {
      int c = i * 256 + tid;
      int row = c >> 2;
      int off = (c & 3) * 8;
      load_lds16(Abase + (int64_t)row * lda + kt * 32 + off, &sA[c * 8]);
      load_lds16(Bbase + (int64_t)row * ldb + kt * 32 + off, &sB[c * 8]);
    }
    __syncthreads();
    bf16x8 av[4], bv[4];
#pragma unroll
    for (int m = 0; m < 4; ++m) av[m] = *(const bf16x8*)&sA[(wr * 64 + m * 16 + l15) * 32 + kh];
#pragma unroll
    for (int n = 0; n < 4; ++n) bv[n] = *(const bf16x8*)&sB[(wc * 64 + n * 16 + l15) * 32 + kh];
#pragma unroll
    for (int m = 0; m < 4; ++m)
#pragma unroll
      for (int n = 0; n < 4; ++n)
        acc[m][n] = __builtin_amdgcn_mfma_f32_16x16x32_bf16(av[m], bv[n], acc[m][n], 0, 0, 0);
    __syncthreads();
  }

#pragma unroll
  for (int m = 0; m < 4; ++m) {
    const int r0 = bm * 128 + wr * 64 + m * 16 + (lane >> 4) * 4;
#pragma unroll
    for (int n = 0; n < 4; ++n) {
      const int c1 = bn * 128 + wc * 64 + n * 16 + l15;
#pragma unroll
      for (int j = 0; j < 4; ++j) epi(r0 + j, c1, acc[m][n][j]);
    }
  }
}

// ---------------- epilogues ----------------
struct EpiQKV {
  bf16* out; const float* bias;
  __device__ void operator()(int r, int c, float v) const {
    out[(int64_t)r * QKVW + c] = (bf16)(v + bias[c]);
  }
};
struct EpiS {
  bf16* S;
  __device__ void operator()(int r, int c, float v) const {
    S[(int64_t)r * cK + c] = (bf16)v;
  }
};
struct EpiPV {
  bf16* out; int coff;
  __device__ void operator()(int r, int c, float v) const {
    out[(int64_t)r * (cH * cHD) + coff + c] = (bf16)v;
  }
};
struct EpiOProj {
  float* x; const float* hidden; const int* topk;
  __device__ void operator()(int r, int c, float v) const {
    int b = r >> 10;
    int t = topk[r];
    x[(int64_t)r * cD + c] = v + hidden[((int64_t)b * cT + t) * cD + c];
  }
};
struct EpiBF16Out {
  bf16* out; int ldc;
  __device__ void operator()(int r, int c, float v) const {
    out[(int64_t)r * ldc + c] = (bf16)v;
  }
};
struct EpiUp {  // act = silu(gate) * up, in place over gate buffer
  bf16* act;
  __device__ void operator()(int r, int c, float v) const {
    int64_t o = (int64_t)r * cFF + c;
    float g = (float)act[o];
    float s = g / (1.f + __expf(-g));
    act[o] = (bf16)(s * v);
  }
};
struct EpiDown {  // x2 = x + acc; upd = sel + (x2-sel)*gate; scatter to d_out
  float* out; const float* x; const float* hidden; const int* topk; const float* gating;
  __device__ void operator()(int r, int c, float v) const {
    int b = r >> 10;
    int t = topk[r];
    float x2 = v + x[(int64_t)r * cD + c];
    int64_t ho = ((int64_t)b * cT + t) * cD + c;
    float sel = hidden[ho];
    out[ho] = sel + (x2 - sel) * gating[r];
  }
};

// ---------------- GEMM kernel wrappers ----------------
template <class Epi>
__global__ __launch_bounds__(256) void gemm_w_kernel(const bf16* __restrict__ A, int lda,
                                                     const bf16* __restrict__ Bm, int ldb,
                                                     int Kd, Epi epi) {
  gemm_core<Epi, false>(A, lda, Bm, ldb, Kd, epi);
}

__global__ __launch_bounds__(256) void gemm_s_kernel(const bf16* __restrict__ qkv_b,
                                                     bf16* __restrict__ Sb) {
  if (blockIdx.x > blockIdx.y) return;  // causal: only lower-triangular tiles
  const int h = blockIdx.z;
  EpiS epi{Sb + (int64_t)h * cK * cK};
  gemm_core<EpiS, false>(qkv_b + h * cHD, QKVW,
                         qkv_b + cH * cHD + (h >> 2) * cHD, QKVW, cHD, epi);
}

__global__ __launch_bounds__(256) void gemm_pv_kernel(const bf16* __restrict__ Pb,
                                                      const bf16* __restrict__ Vt_b,
                                                      bf16* __restrict__ outb) {
  const int h = blockIdx.z;
  EpiPV epi{outb, h * cHD};
  gemm_core<EpiPV, true>(Pb + (int64_t)h * cK * cK, cK,
                         Vt_b + (int64_t)(h >> 2) * cHD * cK, cK, cK, epi);
}

// ---------------- elementwise / staging kernels ----------------
__global__ void copy_f4(const float4* __restrict__ s, float4* __restrict__ d, int64_t n) {
  int64_t i = (int64_t)blockIdx.x * blockDim.x + threadIdx.x;
  const int64_t st = (int64_t)gridDim.x * blockDim.x;
  for (; i < n; i += st) d[i] = s[i];
}

// fp32 (R,C) -> bf16 (C,R) with column offset into a concat buffer
__global__ void wconv(const float* __restrict__ src, bf16* __restrict__ dst,
                      int R, int C, int coff, int ldd) {
  __shared__ float t[32][33];
  const int c0 = blockIdx.x * 32, r0 = blockIdx.y * 32;
  for (int rr = threadIdx.y; rr < 32; rr += 8)
    t[rr][threadIdx.x] = src[(int64_t)(r0 + rr) * C + c0 + threadIdx.x];
  __syncthreads();
  for (int rr = threadIdx.y; rr < 32; rr += 8)
    dst[(int64_t)(c0 + rr + coff) * ldd + r0 + threadIdx.x] = (bf16)t[threadIdx.x][rr];
}

__global__ void biascat(const float* __restrict__ bq, const float* __restrict__ bk,
                        const float* __restrict__ bv, float* __restrict__ o) {
  int i = blockIdx.x * 256 + threadIdx.x;
  if (i < QKVW) o[i] = (i < 2048) ? bq[i] : (i < 2560 ? bk[i - 2048] : bv[i - 2560]);
}

// gather (topk!=null) or direct rows (topk==null) + RMSNorm -> bf16
__global__ void rmsnorm_rows(const float* __restrict__ base, const int* __restrict__ topk,
                             const float* __restrict__ w, bf16* __restrict__ out) {
  const int r = blockIdx.x;
  const float* src;
  if (topk) {
    int t = topk[r];
    src = base + ((int64_t)(r >> 10) * cT + t) * cD;
  } else {
    src = base + (int64_t)r * cD;
  }
  const int tid = threadIdx.x;
  const float4* s4 = (const float4*)src;
  float4 a = s4[tid * 2], b = s4[tid * 2 + 1];
  float ss = a.x * a.x + a.y * a.y + a.z * a.z + a.w * a.w +
             b.x * b.x + b.y * b.y + b.z * b.z + b.w * b.w;
  float tot = blk_reduce<0>(ss);
  float sc = rsqrtf(tot * (1.f / cD) + 1e-6f);
  bf16* o = out + (int64_t)r * cD;
  const int d0 = tid * 8;
  o[d0 + 0] = (bf16)(a.x * sc * w[d0 + 0]);
  o[d0 + 1] = (bf16)(a.y * sc * w[d0 + 1]);
  o[d0 + 2] = (bf16)(a.z * sc * w[d0 + 2]);
  o[d0 + 3] = (bf16)(a.w * sc * w[d0 + 3]);
  o[d0 + 4] = (bf16)(b.x * sc * w[d0 + 4]);
  o[d0 + 5] = (bf16)(b.y * sc * w[d0 + 5]);
  o[d0 + 6] = (bf16)(b.z * sc * w[d0 + 6]);
  o[d0 + 7] = (bf16)(b.w * sc * w[d0 + 7]);
}

__global__ void rope_kernel(bf16* __restrict__ qkv, const float* __restrict__ cosb,
                            const float* __restrict__ sinb, const int* __restrict__ topk) {
  const int r = blockIdx.x;  // b*K + k
  const int b = r >> 10;
  const int t = topk[r];
  const float* cr = cosb + ((int64_t)b * cT + t) * cHD;
  const float* sr = sinb + ((int64_t)b * cT + t) * cHD;
  bf16* rowq = qkv + (int64_t)r * QKVW;
  for (int p = threadIdx.x; p < (cH + cKVH) * 64; p += 256) {
    int hh = p >> 6, d = p & 63;
    bf16* base = (hh < cH) ? (rowq + hh * cHD) : (rowq + cH * cHD + (hh - cH) * cHD);
    float x1 = (float)base[d], x2 = (float)base[d + 64];
    float c1 = cr[d], s1 = sr[d], c2 = cr[d + 64], s2 = sr[d + 64];
    base[d] = (bf16)(x1 * c1 - x2 * s1);
    base[d + 64] = (bf16)(x2 * c2 + x1 * s2);
  }
}

// v-part of qkv -> Vt (B,KVH,HD,K) bf16
__global__ void vtrans(const bf16* __restrict__ qkv, bf16* __restrict__ Vt) {
  __shared__ bf16 t[32][33];
  const int bz = blockIdx.z, b = bz >> 2, kv = bz & 3;
  const int k0 = blockIdx.x * 32, d0 = blockIdx.y * 32;
  for (int rr = threadIdx.y; rr < 32; rr += 8)
    t[rr][threadIdx.x] =
        qkv[(int64_t)(b * cK + k0 + rr) * QKVW + cH * cHD + cKVH * cHD + kv * cHD + d0 + threadIdx.x];
  __syncthreads();
  for (int rr = threadIdx.y; rr < 32; rr += 8)
    Vt[((int64_t)(b * cKVH + kv) * cHD + d0 + rr) * cK + k0 + threadIdx.x] = t[threadIdx.x][rr];
}

// causal row softmax over S (16,1024,1024) bf16, in place, zero-pad to 128 tile
__global__ void softmax_causal(bf16* __restrict__ S) {
  const int i = blockIdx.x, h = blockIdx.y;
  bf16* row = S + ((int64_t)h * cK + i) * cK;
  const int len = i + 1;
  const float scale = 0.08838834764831845f;  // 1/sqrt(128)
  const int tid = threadIdx.x;
  float vals[4];
  int cnt = 0;
  float m = -3.0e38f;
  for (int j = tid; j < len; j += 256) {
    float v = (float)row[j] * scale;
    vals[cnt++] = v;
    m = fmaxf(m, v);
  }
  float M = blk_reduce<1>(m);
  float s = 0.f;
  for (int q = 0; q < cnt; ++q) {
    float e = __expf(vals[q] - M);
    vals[q] = e;
    s += e;
  }
  float SUM = blk_reduce<0>(s);
  float inv = 1.f / SUM;
  int q2 = 0;
  for (int j = tid; j < len; j += 256) row[j] = (bf16)(vals[q2++] * inv);
  const int pad = ((i >> 7) + 1) << 7;
  for (int j = len + tid; j < pad; j += 256) row[j] = (bf16)0.f;
}

}  // namespace

extern "C" void kernel_launch(void* const* d_in, const int* in_sizes, int n_in,
                              void* d_out, int out_size, void* d_ws, size_t ws_size,
                              hipStream_t stream) {
  const float* hidden = (const float*)d_in[0];
  const int* topk = (const int*)d_in[1];
  const float* gating = (const float*)d_in[2];
  const float* cosb = (const float*)d_in[3];
  const float* sinb = (const float*)d_in[4];
  const float* Wq = (const float*)d_in[5];
  const float* bq = (const float*)d_in[6];
  const float* Wk = (const float*)d_in[7];
  const float* bk = (const float*)d_in[8];
  const float* Wv = (const float*)d_in[9];
  const float* bv = (const float*)d_in[10];
  const float* Wo = (const float*)d_in[11];
  const float* wg = (const float*)d_in[12];
  const float* wu = (const float*)d_in[13];
  const float* wd = (const float*)d_in[14];
  const float* ln1 = (const float*)d_in[15];
  const float* ln2 = (const float*)d_in[16];
  float* out = (float*)d_out;
  (void)in_sizes; (void)n_in; (void)out_size; (void)ws_size;

  char* ws = (char*)d_ws;
  size_t off = 0;
  auto alloc = [&](size_t bytes) {
    char* p = ws + off;
    off += (bytes + 255) & ~(size_t)255;
    return p;
  };
  bf16* wt_qkv = (bf16*)alloc((size_t)QKVW * cD * 2);
  bf16* wt_o = (bf16*)alloc((size_t)cD * cD * 2);
  bf16* wt_g = (bf16*)alloc((size_t)cFF * cD * 2);
  bf16* wt_u = (bf16*)alloc((size_t)cFF * cD * 2);
  bf16* wt_d = (bf16*)alloc((size_t)cD * cFF * 2);
  float* bias_cat = (float*)alloc((size_t)QKVW * 4);
  bf16* hbuf = (bf16*)alloc((size_t)cM * cD * 2);
  bf16* qkv = (bf16*)alloc((size_t)cM * QKVW * 2);
  bf16* vt = (bf16*)alloc((size_t)cB * cKVH * cHD * cK * 2);
  bf16* attnout = (bf16*)alloc((size_t)cM * cD * 2);
  float* xbuf = (float*)alloc((size_t)cM * cD * 4);
  bf16* actbuf = (bf16*)alloc((size_t)cM * cFF * 2);
  bf16* sbuf = (bf16*)alloc((size_t)cH * cK * cK * 2);

  // d_out = hidden_states (scatter overwrites selected rows later)
  copy_f4<<<2048, 256, 0, stream>>>((const float4*)hidden, (float4*)out,
                                    (int64_t)cB * cT * cD / 4);

  const dim3 tb(32, 8);
  wconv<<<dim3(cD / 32, cD / 32), tb, 0, stream>>>(Wq, wt_qkv, cD, cD, 0, cD);
  wconv<<<dim3(512 / 32, cD / 32), tb, 0, stream>>>(Wk, wt_qkv, cD, 512, 2048, cD);
  wconv<<<dim3(512 / 32, cD / 32), tb, 0, stream>>>(Wv, wt_qkv, cD, 512, 2560, cD);
  wconv<<<dim3(cD / 32, cD / 32), tb, 0, stream>>>(Wo, wt_o, cD, cD, 0, cD);
  wconv<<<dim3(cFF / 32, cD / 32), tb, 0, stream>>>(wg, wt_g, cD, cFF, 0, cD);
  wconv<<<dim3(cFF / 32, cD / 32), tb, 0, stream>>>(wu, wt_u, cD, cFF, 0, cD);
  wconv<<<dim3(cD / 32, cFF / 32), tb, 0, stream>>>(wd, wt_d, cFF, cD, 0, cFF);
  biascat<<<(QKVW + 255) / 256, 256, 0, stream>>>(bq, bk, bv, bias_cat);

  // gather + rmsnorm1
  rmsnorm_rows<<<cM, 256, 0, stream>>>(hidden, topk, ln1, hbuf);
  // qkv projection (+bias)
  gemm_w_kernel<EpiQKV><<<dim3(QKVW / 128, cM / 128), 256, 0, stream>>>(
      hbuf, cD, wt_qkv, cD, cD, EpiQKV{qkv, bias_cat});
  rope_kernel<<<cM, 256, 0, stream>>>(qkv, cosb, sinb, topk);
  vtrans<<<dim3(cK / 32, cHD / 32, cB * cKVH), tb, 0, stream>>>(qkv, vt);

  for (int b = 0; b < cB; ++b) {
    const bf16* qkv_b = qkv + (int64_t)b * cK * QKVW;
    gemm_s_kernel<<<dim3(cK / 128, cK / 128, cH), 256, 0, stream>>>(qkv_b, sbuf);
    softmax_causal<<<dim3(cK, cH), 256, 0, stream>>>(sbuf);
    gemm_pv_kernel<<<dim3(cHD / 128, cK / 128, cH), 256, 0, stream>>>(
        sbuf, vt + (int64_t)b * cKVH * cHD * cK, attnout + (int64_t)b * cK * cD);
  }

  // o-proj + gathered residual -> x (fp32)
  gemm_w_kernel<EpiOProj><<<dim3(cD / 128, cM / 128), 256, 0, stream>>>(
      attnout, cD, wt_o, cD, cD, EpiOProj{xbuf, hidden, topk});
  // rmsnorm2
  rmsnorm_rows<<<cM, 256, 0, stream>>>(xbuf, nullptr, ln2, hbuf);
  // gate, then act = silu(gate)*up in place
  gemm_w_kernel<EpiBF16Out><<<dim3(cFF / 128, cM / 128), 256, 0, stream>>>(
      hbuf, cD, wt_g, cD, cD, EpiBF16Out{actbuf, cFF});
  gemm_w_kernel<EpiUp><<<dim3(cFF / 128, cM / 128), 256, 0, stream>>>(
      hbuf, cD, wt_u, cD, cD, EpiUp{actbuf});
  // down + residual + gating + scatter into d_out
  gemm_w_kernel<EpiDown><<<dim3(cD / 128, cM / 128), 256, 0, stream>>>(
      actbuf, cFF, wt_d, cFF, cFF, EpiDown{out, xbuf, hidden, topk, gating});
}

// Round 3
// 1069.280 us; speedup vs baseline: 1.2065x; 1.2065x over previous
//
#include <hip/hip_runtime.h>
#include <stdint.h>

typedef __bf16 bf16;
typedef __attribute__((ext_vector_type(8))) __bf16 bf16x8;
typedef __attribute__((ext_vector_type(4))) float f32x4;

namespace {

constexpr int cB = 4, cT = 4096, cD = 2048, cK = 1024, cH = 16, cKVH = 4, cHD = 128, cFF = 8192;
constexpr int cM = cB * cK;                 // 4096 gathered rows
constexpr int QKVW = cH * cHD + 2 * cKVH * cHD; // 3072

__device__ __forceinline__ void load_lds16(const void* g, void* l) {
  __builtin_amdgcn_global_load_lds((const __attribute__((address_space(1))) void*)g,
                                   (__attribute__((address_space(3))) void*)l, 16, 0, 0);
}

// ---------------- block reduce (256 threads = 4 waves) ----------------
template <int OP>  // 0 = sum, 1 = max
__device__ __forceinline__ float blk_reduce(float v) {
  __shared__ float sm[5];
  const int tid = threadIdx.x, lane = tid & 63, wid = tid >> 6;
#pragma unroll
  for (int o = 32; o; o >>= 1) {
    float o2 = __shfl_down(v, o, 64);
    v = OP ? fmaxf(v, o2) : v + o2;
  }
  if (lane == 0) sm[wid] = v;
  __syncthreads();
  if (tid == 0) {
    float r = sm[0];
#pragma unroll
    for (int i = 1; i < 4; ++i) r = OP ? fmaxf(r, sm[i]) : r + sm[i];
    sm[4] = r;
  }
  __syncthreads();
  float r = sm[4];
  __syncthreads();
  return r;
}

// ================= deep-pipelined 256-row MFMA GEMM: C = A * B^T =================
// A: M x Kd row-major (lda), B: N x Kd row-major (ldb). BM=256, BK=32.
// 8 waves (512 thr), WM x WN wave grid, 4-slot LDS ring, counted vmcnt, raw barriers,
// XOR-swizzled LDS (pre-swizzled global source, swizzled ds_read_b128).
// TAIL FIX (round 2 race): the counted vmcnt(2L) only proves tile t+1 landed while
// 3 stage-groups are in flight; the last 3 iterations are peeled with vmcnt(0).
template <int BN, int WM, int WN, class Epi>
__global__ __launch_bounds__(512, 2) void gemm256(const bf16* __restrict__ A, int lda,
                                                  const bf16* __restrict__ Bm, int ldb,
                                                  int Kd, int GM, Epi epi) {
  constexpr int BM = 256;
  constexpr int FM = BM / WM / 16;
  constexpr int FN = BN / WN / 16;
  constexpr int ACALLS = 2;          // 256 rows * 64B / (512 thr * 16B)
  constexpr int BCALLS = BN / 128;
  constexpr int L = ACALLS + BCALLS; // vmem instrs per K-tile per thread
  constexpr int SLOTA = BM * 64;     // bytes per A K-tile (BK=32 -> 64B rows)
  constexpr int SLOTB = BN * 64;
  constexpr int SLOT = SLOTA + SLOTB;
  __shared__ __align__(16) char lds[4 * SLOT];

  const int tid = threadIdx.x;
  const int lane = tid & 63;
  const int wid = tid >> 6;
  const int l15 = lane & 15, lq = lane >> 4;
  const int wr = wid / WN, wc = wid % WN;

  // bijective XCD remap (m204), bm-fastest ordering for per-XCD B-panel L2 residency
  const int nwg = gridDim.x;
  const int orig = blockIdx.x;
  const int q = nwg >> 3, r = nwg & 7;
  const int xcd = orig & 7, loc = orig >> 3;
  const int wg = (xcd < r ? xcd * (q + 1) : r * (q + 1) + (xcd - r) * q) + loc;
  const int bm = wg % GM, bn = wg / GM;

  const bf16* Abase = A + (int64_t)bm * BM * lda;
  const bf16* Bbase = Bm + (int64_t)bn * BN * ldb;

  // staging: LDS linear chunk -> pre-swizzled global source
  const bf16* srcA[ACALLS];
  int dstA[ACALLS];
#pragma unroll
  for (int c2 = 0; c2 < ACALLS; ++c2) {
    const int chunk = c2 * 512 + tid;
    const int row = chunk >> 2, pc = chunk & 3;
    const int lc = pc ^ ((row >> 1) & 3);
    srcA[c2] = Abase + (int64_t)row * lda + lc * 8;
    dstA[c2] = chunk * 16;
  }
  const bf16* srcB[BCALLS];
  int dstB[BCALLS];
#pragma unroll
  for (int c2 = 0; c2 < BCALLS; ++c2) {
    const int chunk = c2 * 512 + tid;
    const int row = chunk >> 2, pc = chunk & 3;
    const int lc = pc ^ ((row >> 1) & 3);
    srcB[c2] = Bbase + (int64_t)row * ldb + lc * 8;
    dstB[c2] = chunk * 16;
  }

  // fragment read offsets (swizzled)
  int offA[FM], offB[FN];
#pragma unroll
  for (int m = 0; m < FM; ++m) {
    const int row = wr * (BM / WM) + m * 16 + l15;
    offA[m] = row * 64 + (lq ^ ((row >> 1) & 3)) * 16;
  }
#pragma unroll
  for (int n = 0; n < FN; ++n) {
    const int row = wc * (BN / WN) + n * 16 + l15;
    offB[n] = SLOTA + row * 64 + (lq ^ ((row >> 1) & 3)) * 16;
  }

  const int KT = Kd >> 5;
  auto stage = [&](int t) {
    char* sb = lds + (size_t)(t & 3) * SLOT;
#pragma unroll
    for (int c2 = 0; c2 < ACALLS; ++c2)
      load_lds16(srcA[c2] + t * 32, sb + dstA[c2]);
#pragma unroll
    for (int c2 = 0; c2 < BCALLS; ++c2)
      load_lds16(srcB[c2] + t * 32, sb + SLOTA + dstB[c2]);
  };
  auto compute = [&](int t, f32x4 (&acc)[FM][FN]) {
    const char* sb = lds + (size_t)(t & 3) * SLOT;
    bf16x8 av[FM], bv[FN];
#pragma unroll
    for (int m = 0; m < FM; ++m) av[m] = *(const bf16x8*)(sb + offA[m]);
#pragma unroll
    for (int n = 0; n < FN; ++n) bv[n] = *(const bf16x8*)(sb + offB[n]);
    __builtin_amdgcn_s_setprio(1);
#pragma unroll
    for (int m = 0; m < FM; ++m)
#pragma unroll
      for (int n = 0; n < FN; ++n)
        acc[m][n] = __builtin_amdgcn_mfma_f32_16x16x32_bf16(av[m], bv[n], acc[m][n], 0, 0, 0);
    __builtin_amdgcn_s_setprio(0);
  };

  f32x4 acc[FM][FN] = {};

  stage(0);
  stage(1);
  stage(2);
  if constexpr (L == 4) asm volatile("s_waitcnt vmcnt(8)" ::: "memory");
  else                  asm volatile("s_waitcnt vmcnt(6)" ::: "memory");
  __builtin_amdgcn_s_barrier();
  __builtin_amdgcn_sched_barrier(0);

  // main loop: always 3 stage-groups in flight -> counted vmcnt proves tile t+1 landed
  for (int t = 0; t < KT - 3; ++t) {
    stage(t + 3);
    compute(t, acc);
    // tile t+1 landed; tiles t+2, t+3 stay in flight (counted vmcnt, never 0)
    if constexpr (L == 4) asm volatile("s_waitcnt vmcnt(8)" ::: "memory");
    else                  asm volatile("s_waitcnt vmcnt(6)" ::: "memory");
    __builtin_amdgcn_s_barrier();
    __builtin_amdgcn_sched_barrier(0);
  }
  // peeled tail: no new stages in flight, counted vmcnt would be a no-op -> full drain
  for (int t = KT - 3; t < KT; ++t) {
    compute(t, acc);
    asm volatile("s_waitcnt vmcnt(0)" ::: "memory");
    __builtin_amdgcn_s_barrier();
    __builtin_amdgcn_sched_barrier(0);
  }

#pragma unroll
  for (int m = 0; m < FM; ++m) {
    const int r0 = bm * BM + wr * (BM / WM) + m * 16 + lq * 4;
#pragma unroll
    for (int n = 0; n < FN; ++n) {
      const int c1 = bn * BN + wc * (BN / WN) + n * 16 + l15;
#pragma unroll
      for (int j = 0; j < 4; ++j) epi(r0 + j, c1, acc[m][n][j]);
    }
  }
}

// ------------- old 128x128 (BK=32) core, kept for attention GEMMs -------------
template <class Epi, bool KLIMIT>
__device__ __forceinline__ void gemm_core(const bf16* __restrict__ A, int lda,
                                          const bf16* __restrict__ Bm, int ldb,
                                          int Kd, const Epi& epi) {
  __shared__ __align__(16) bf16 sA[128 * 32];
  __shared__ __align__(16) bf16 sB[128 * 32];
  const int tid = threadIdx.x;
  const int lane = tid & 63;
  const int wid = tid >> 6;
  const int wr = wid >> 1, wc = wid & 1;
  const int bm = blockIdx.y, bn = blockIdx.x;
  const int l15 = lane & 15;
  const int kh = (lane >> 4) * 8;

  f32x4 acc[4][4] = {};
  int ktiles = Kd >> 5;
  if (KLIMIT) {
    int lim = ((bm + 1) * 128) >> 5;
    if (lim < ktiles) ktiles = lim;
  }
  const bf16* Abase = A + (int64_t)bm * 128 * lda;
  const bf16* Bbase = Bm + (int64_t)bn * 128 * ldb;

  for (int kt = 0; kt < ktiles; ++kt) {
#pragma unroll
    for (int i = 0; i < 2; ++i) {
      int c = i * 256 + tid;
      int row = c >> 2;
      int off = (c & 3) * 8;
      load_lds16(Abase + (int64_t)row * lda + kt * 32 + off, &sA[c * 8]);
      load_lds16(Bbase + (int64_t)row * ldb + kt * 32 + off, &sB[c * 8]);
    }
    __syncthreads();
    bf16x8 av[4], bv[4];
#pragma unroll
    for (int m = 0; m < 4; ++m) av[m] = *(const bf16x8*)&sA[(wr * 64 + m * 16 + l15) * 32 + kh];
#pragma unroll
    for (int n = 0; n < 4; ++n) bv[n] = *(const bf16x8*)&sB[(wc * 64 + n * 16 + l15) * 32 + kh];
#pragma unroll
    for (int m = 0; m < 4; ++m)
#pragma unroll
      for (int n = 0; n < 4; ++n)
        acc[m][n] = __builtin_amdgcn_mfma_f32_16x16x32_bf16(av[m], bv[n], acc[m][n], 0, 0, 0);
    __syncthreads();
  }

#pragma unroll
  for (int m = 0; m < 4; ++m) {
    const int r0 = bm * 128 + wr * 64 + m * 16 + (lane >> 4) * 4;
#pragma unroll
    for (int n = 0; n < 4; ++n) {
      const int c1 = bn * 128 + wc * 64 + n * 16 + l15;
#pragma unroll
      for (int j = 0; j < 4; ++j) epi(r0 + j, c1, acc[m][n][j]);
    }
  }
}

// ---------------- epilogues ----------------
struct EpiQKV {
  bf16* out; const float* bias;
  __device__ void operator()(int r, int c, float v) const {
    out[(int64_t)r * QKVW + c] = (bf16)(v + bias[c]);
  }
};
struct EpiS {
  bf16* S;
  __device__ void operator()(int r, int c, float v) const {
    S[(int64_t)r * cK + c] = (bf16)v;
  }
};
struct EpiPV {
  bf16* out; int coff;
  __device__ void operator()(int r, int c, float v) const {
    out[(int64_t)r * (cH * cHD) + coff + c] = (bf16)v;
  }
};
struct EpiOProj {
  float* x; const float* hidden; const int* topk;
  __device__ void operator()(int r, int c, float v) const {
    int b = r >> 10;
    int t = topk[r];
    x[(int64_t)r * cD + c] = v + hidden[((int64_t)b * cT + t) * cD + c];
  }
};
struct EpiBF16Out {
  bf16* out; int ldc;
  __device__ void operator()(int r, int c, float v) const {
    out[(int64_t)r * ldc + c] = (bf16)v;
  }
};
struct EpiUp {  // act = silu(gate) * up, in place over gate buffer
  bf16* act;
  __device__ void operator()(int r, int c, float v) const {
    int64_t o = (int64_t)r * cFF + c;
    float g = (float)act[o];
    float s = g / (1.f + __expf(-g));
    act[o] = (bf16)(s * v);
  }
};
struct EpiDown {  // x2 = x + acc; upd = sel + (x2-sel)*gate; scatter to d_out
  float* out; const float* x; const float* hidden; const int* topk; const float* gating;
  __device__ void operator()(int r, int c, float v) const {
    int b = r >> 10;
    int t = topk[r];
    float x2 = v + x[(int64_t)r * cD + c];
    int64_t ho = ((int64_t)b * cT + t) * cD + c;
    float sel = hidden[ho];
    out[ho] = sel + (x2 - sel) * gating[r];
  }
};

// ---------------- attention GEMM kernels (old core) ----------------
__global__ __launch_bounds__(256) void gemm_s_kernel(const bf16* __restrict__ qkv_b,
                                                     bf16* __restrict__ Sb) {
  if (blockIdx.x > blockIdx.y) return;  // causal: only lower-triangular tiles
  const int h = blockIdx.z;
  EpiS epi{Sb + (int64_t)h * cK * cK};
  gemm_core<EpiS, false>(qkv_b + h * cHD, QKVW,
                         qkv_b + cH * cHD + (h >> 2) * cHD, QKVW, cHD, epi);
}

__global__ __launch_bounds__(256) void gemm_pv_kernel(const bf16* __restrict__ Pb,
                                                      const bf16* __restrict__ Vt_b,
                                                      bf16* __restrict__ outb) {
  const int h = blockIdx.z;
  EpiPV epi{outb, h * cHD};
  gemm_core<EpiPV, true>(Pb + (int64_t)h * cK * cK, cK,
                         Vt_b + (int64_t)(h >> 2) * cHD * cK, cK, cK, epi);
}

// ---------------- elementwise / staging kernels ----------------
__global__ void copy_f4(const float4* __restrict__ s, float4* __restrict__ d, int64_t n) {
  int64_t i = (int64_t)blockIdx.x * blockDim.x + threadIdx.x;
  const int64_t st = (int64_t)gridDim.x * blockDim.x;
  for (; i < n; i += st) d[i] = s[i];
}

// fp32 (R,C) -> bf16 (C,R) with column offset into a concat buffer
__global__ void wconv(const float* __restrict__ src, bf16* __restrict__ dst,
                      int R, int C, int coff, int ldd) {
  __shared__ float t[32][33];
  const int c0 = blockIdx.x * 32, r0 = blockIdx.y * 32;
  for (int rr = threadIdx.y; rr < 32; rr += 8)
    t[rr][threadIdx.x] = src[(int64_t)(r0 + rr) * C + c0 + threadIdx.x];
  __syncthreads();
  for (int rr = threadIdx.y; rr < 32; rr += 8)
    dst[(int64_t)(c0 + rr + coff) * ldd + r0 + threadIdx.x] = (bf16)t[threadIdx.x][rr];
}

__global__ void biascat(const float* __restrict__ bq, const float* __restrict__ bk,
                        const float* __restrict__ bv, float* __restrict__ o) {
  int i = blockIdx.x * 256 + threadIdx.x;
  if (i < QKVW) o[i] = (i < 2048) ? bq[i] : (i < 2560 ? bk[i - 2048] : bv[i - 2560]);
}

// gather (topk!=null) or direct rows (topk==null) + RMSNorm -> bf16
__global__ void rmsnorm_rows(const float* __restrict__ base, const int* __restrict__ topk,
                             const float* __restrict__ w, bf16* __restrict__ out) {
  const int r = blockIdx.x;
  const float* src;
  if (topk) {
    int t = topk[r];
    src = base + ((int64_t)(r >> 10) * cT + t) * cD;
  } else {
    src = base + (int64_t)r * cD;
  }
  const int tid = threadIdx.x;
  const float4* s4 = (const float4*)src;
  float4 a = s4[tid * 2], b = s4[tid * 2 + 1];
  float ss = a.x * a.x + a.y * a.y + a.z * a.z + a.w * a.w +
             b.x * b.x + b.y * b.y + b.z * b.z + b.w * b.w;
  float tot = blk_reduce<0>(ss);
  float sc = rsqrtf(tot * (1.f / cD) + 1e-6f);
  bf16* o = out + (int64_t)r * cD;
  const int d0 = tid * 8;
  o[d0 + 0] = (bf16)(a.x * sc * w[d0 + 0]);
  o[d0 + 1] = (bf16)(a.y * sc * w[d0 + 1]);
  o[d0 + 2] = (bf16)(a.z * sc * w[d0 + 2]);
  o[d0 + 3] = (bf16)(a.w * sc * w[d0 + 3]);
  o[d0 + 4] = (bf16)(b.x * sc * w[d0 + 4]);
  o[d0 + 5] = (bf16)(b.y * sc * w[d0 + 5]);
  o[d0 + 6] = (bf16)(b.z * sc * w[d0 + 6]);
  o[d0 + 7] = (bf16)(b.w * sc * w[d0 + 7]);
}

__global__ void rope_kernel(bf16* __restrict__ qkv, const float* __restrict__ cosb,
                            const float* __restrict__ sinb, const int* __restrict__ topk) {
  const int r = blockIdx.x;  // b*K + k
  const int b = r >> 10;
  const int t = topk[r];
  const float* cr = cosb + ((int64_t)b * cT + t) * cHD;
  const float* sr = sinb + ((int64_t)b * cT + t) * cHD;
  bf16* rowq = qkv + (int64_t)r * QKVW;
  for (int p = threadIdx.x; p < (cH + cKVH) * 64; p += 256) {
    int hh = p >> 6, d = p & 63;
    bf16* base = (hh < cH) ? (rowq + hh * cHD) : (rowq + cH * cHD + (hh - cH) * cHD);
    float x1 = (float)base[d], x2 = (float)base[d + 64];
    float c1 = cr[d], s1 = sr[d], c2 = cr[d + 64], s2 = sr[d + 64];
    base[d] = (bf16)(x1 * c1 - x2 * s1);
    base[d + 64] = (bf16)(x2 * c2 + x1 * s2);
  }
}

// v-part of qkv -> Vt (B,KVH,HD,K) bf16
__global__ void vtrans(const bf16* __restrict__ qkv, bf16* __restrict__ Vt) {
  __shared__ bf16 t[32][33];
  const int bz = blockIdx.z, b = bz >> 2, kv = bz & 3;
  const int k0 = blockIdx.x * 32, d0 = blockIdx.y * 32;
  for (int rr = threadIdx.y; rr < 32; rr += 8)
    t[rr][threadIdx.x] =
        qkv[(int64_t)(b * cK + k0 + rr) * QKVW + cH * cHD + cKVH * cHD + kv * cHD + d0 + threadIdx.x];
  __syncthreads();
  for (int rr = threadIdx.y; rr < 32; rr += 8)
    Vt[((int64_t)(b * cKVH + kv) * cHD + d0 + rr) * cK + k0 + threadIdx.x] = t[threadIdx.x][rr];
}

// causal row softmax over S (16,1024,1024) bf16, in place, zero-pad to 128 tile
__global__ void softmax_causal(bf16* __restrict__ S) {
  const int i = blockIdx.x, h = blockIdx.y;
  bf16* row = S + ((int64_t)h * cK + i) * cK;
  const int len = i + 1;
  const float scale = 0.08838834764831845f;  // 1/sqrt(128)
  const int tid = threadIdx.x;
  float vals[4];
  int cnt = 0;
  float m = -3.0e38f;
  for (int j = tid; j < len; j += 256) {
    float v = (float)row[j] * scale;
    vals[cnt++] = v;
    m = fmaxf(m, v);
  }
  float M = blk_reduce<1>(m);
  float s = 0.f;
  for (int q = 0; q < cnt; ++q) {
    float e = __expf(vals[q] - M);
    vals[q] = e;
    s += e;
  }
  float SUM = blk_reduce<0>(s);
  float inv = 1.f / SUM;
  int q2 = 0;
  for (int j = tid; j < len; j += 256) row[j] = (bf16)(vals[q2++] * inv);
  const int pad = ((i >> 7) + 1) << 7;
  for (int j = len + tid; j < pad; j += 256) row[j] = (bf16)0.f;
}

}  // namespace

extern "C" void kernel_launch(void* const* d_in, const int* in_sizes, int n_in,
                              void* d_out, int out_size, void* d_ws, size_t ws_size,
                              hipStream_t stream) {
  const float* hidden = (const float*)d_in[0];
  const int* topk = (const int*)d_in[1];
  const float* gating = (const float*)d_in[2];
  const float* cosb = (const float*)d_in[3];
  const float* sinb = (const float*)d_in[4];
  const float* Wq = (const float*)d_in[5];
  const float* bq = (const float*)d_in[6];
  const float* Wk = (const float*)d_in[7];
  const float* bk = (const float*)d_in[8];
  const float* Wv = (const float*)d_in[9];
  const float* bv = (const float*)d_in[10];
  const float* Wo = (const float*)d_in[11];
  const float* wg = (const float*)d_in[12];
  const float* wu = (const float*)d_in[13];
  const float* wd = (const float*)d_in[14];
  const float* ln1 = (const float*)d_in[15];
  const float* ln2 = (const float*)d_in[16];
  float* out = (float*)d_out;
  (void)in_sizes; (void)n_in; (void)out_size; (void)ws_size;

  char* ws = (char*)d_ws;
  size_t off = 0;
  auto alloc = [&](size_t bytes) {
    char* p = ws + off;
    off += (bytes + 255) & ~(size_t)255;
    return p;
  };
  bf16* wt_qkv = (bf16*)alloc((size_t)QKVW * cD * 2);
  bf16* wt_o = (bf16*)alloc((size_t)cD * cD * 2);
  bf16* wt_g = (bf16*)alloc((size_t)cFF * cD * 2);
  bf16* wt_u = (bf16*)alloc((size_t)cFF * cD * 2);
  bf16* wt_d = (bf16*)alloc((size_t)cD * cFF * 2);
  float* bias_cat = (float*)alloc((size_t)QKVW * 4);
  bf16* hbuf = (bf16*)alloc((size_t)cM * cD * 2);
  bf16* qkv = (bf16*)alloc((size_t)cM * QKVW * 2);
  bf16* vt = (bf16*)alloc((size_t)cB * cKVH * cHD * cK * 2);
  bf16* attnout = (bf16*)alloc((size_t)cM * cD * 2);
  float* xbuf = (float*)alloc((size_t)cM * cD * 4);
  bf16* actbuf = (bf16*)alloc((size_t)cM * cFF * 2);
  bf16* sbuf = (bf16*)alloc((size_t)cH * cK * cK * 2);

  // d_out = hidden_states (scatter overwrites selected rows later)
  copy_f4<<<2048, 256, 0, stream>>>((const float4*)hidden, (float4*)out,
                                    (int64_t)cB * cT * cD / 4);

  const dim3 tb(32, 8);
  wconv<<<dim3(cD / 32, cD / 32), tb, 0, stream>>>(Wq, wt_qkv, cD, cD, 0, cD);
  wconv<<<dim3(512 / 32, cD / 32), tb, 0, stream>>>(Wk, wt_qkv, cD, 512, 2048, cD);
  wconv<<<dim3(512 / 32, cD / 32), tb, 0, stream>>>(Wv, wt_qkv, cD, 512, 2560, cD);
  wconv<<<dim3(cD / 32, cD / 32), tb, 0, stream>>>(Wo, wt_o, cD, cD, 0, cD);
  wconv<<<dim3(cFF / 32, cD / 32), tb, 0, stream>>>(wg, wt_g, cD, cFF, 0, cD);
  wconv<<<dim3(cFF / 32, cD / 32), tb, 0, stream>>>(wu, wt_u, cD, cFF, 0, cD);
  wconv<<<dim3(cD / 32, cFF / 32), tb, 0, stream>>>(wd, wt_d, cFF, cD, 0, cFF);
  biascat<<<(QKVW + 255) / 256, 256, 0, stream>>>(bq, bk, bv, bias_cat);

  // gather + rmsnorm1
  rmsnorm_rows<<<cM, 256, 0, stream>>>(hidden, topk, ln1, hbuf);
  // qkv projection (+bias)
  gemm256<256, 2, 4, EpiQKV><<<16 * (QKVW / 256), 512, 0, stream>>>(
      hbuf, cD, wt_qkv, cD, cD, 16, EpiQKV{qkv, bias_cat});
  rope_kernel<<<cM, 256, 0, stream>>>(qkv, cosb, sinb, topk);
  vtrans<<<dim3(cK / 32, cHD / 32, cB * cKVH), tb, 0, stream>>>(qkv, vt);

  for (int b = 0; b < cB; ++b) {
    const bf16* qkv_b = qkv + (int64_t)b * cK * QKVW;
    gemm_s_kernel<<<dim3(cK / 128, cK / 128, cH), 256, 0, stream>>>(qkv_b, sbuf);
    softmax_causal<<<dim3(cK, cH), 256, 0, stream>>>(sbuf);
    gemm_pv_kernel<<<dim3(cHD / 128, cK / 128, cH), 256, 0, stream>>>(
        sbuf, vt + (int64_t)b * cKVH * cHD * cK, attnout + (int64_t)b * cK * cD);
  }

  // o-proj + gathered residual -> x (fp32)
  gemm256<128, 4, 2, EpiOProj><<<16 * (cD / 128), 512, 0, stream>>>(
      attnout, cD, wt_o, cD, cD, 16, EpiOProj{xbuf, hidden, topk});
  // rmsnorm2
  rmsnorm_rows<<<cM, 256, 0, stream>>>(xbuf, nullptr, ln2, hbuf);
  // gate, then act = silu(gate)*up in place
  gemm256<256, 2, 4, EpiBF16Out><<<16 * (cFF / 256), 512, 0, stream>>>(
      hbuf, cD, wt_g, cD, cD, 16, EpiBF16Out{actbuf, cFF});
  gemm256<256, 2, 4, EpiUp><<<16 * (cFF / 256), 512, 0, stream>>>(
      hbuf, cD, wt_u, cD, cD, 16, EpiUp{actbuf});
  // down + residual + gating + scatter into d_out
  gemm256<128, 4, 2, EpiDown><<<16 * (cD / 128), 512, 0, stream>>>(
      actbuf, cFF, wt_d, cFF, cFF, 16, EpiDown{out, xbuf, hidden, topk, gating});
}

// Round 4
// 1065.483 us; speedup vs baseline: 1.2108x; 1.0036x over previous
//
#include <hip/hip_runtime.h>
#include <stdint.h>

typedef __bf16 bf16;
typedef __attribute__((ext_vector_type(8))) __bf16 bf16x8;
typedef __attribute__((ext_vector_type(4))) float f32x4;

namespace {

constexpr int cB = 4, cT = 4096, cD = 2048, cK = 1024, cH = 16, cKVH = 4, cHD = 128, cFF = 8192;
constexpr int cM = cB * cK;                 // 4096 gathered rows
constexpr int QKVW = cH * cHD + 2 * cKVH * cHD; // 3072

__device__ __forceinline__ void load_lds16(const void* g, void* l) {
  __builtin_amdgcn_global_load_lds((const __attribute__((address_space(1))) void*)g,
                                   (__attribute__((address_space(3))) void*)l, 16, 0, 0);
}

template <int N>
__device__ __forceinline__ void waitcnt_vm() {
  if constexpr (N == 0) asm volatile("s_waitcnt vmcnt(0)" ::: "memory");
  else if constexpr (N == 3) asm volatile("s_waitcnt vmcnt(3)" ::: "memory");
  else if constexpr (N == 4) asm volatile("s_waitcnt vmcnt(4)" ::: "memory");
  else if constexpr (N == 6) asm volatile("s_waitcnt vmcnt(6)" ::: "memory");
  else if constexpr (N == 8) asm volatile("s_waitcnt vmcnt(8)" ::: "memory");
  else static_assert(N == 0, "unsupported vmcnt literal");
}

// ---------------- block reduce (256 threads = 4 waves) ----------------
template <int OP>  // 0 = sum, 1 = max
__device__ __forceinline__ float blk_reduce(float v) {
  __shared__ float sm[5];
  const int tid = threadIdx.x, lane = tid & 63, wid = tid >> 6;
#pragma unroll
  for (int o = 32; o; o >>= 1) {
    float o2 = __shfl_down(v, o, 64);
    v = OP ? fmaxf(v, o2) : v + o2;
  }
  if (lane == 0) sm[wid] = v;
  __syncthreads();
  if (tid == 0) {
    float r = sm[0];
#pragma unroll
    for (int i = 1; i < 4; ++i) r = OP ? fmaxf(r, sm[i]) : r + sm[i];
    sm[4] = r;
  }
  __syncthreads();
  float r = sm[4];
  __syncthreads();
  return r;
}

// ================= deep-pipelined 256-row MFMA GEMM: C = A * B^T =================
// A: M x Kd row-major (lda), B: N x Kd row-major (ldb). BM=256, BK=32.
// 8 waves (512 thr), WM x WN wave grid, RING-slot LDS ring (prefetch depth D=RING-1),
// counted vmcnt, raw barriers, XOR-swizzled LDS (pre-swizzled global src + swizzled read).
// vmcnt ledger: end of main iter t waits (D-1)*L -> tile t+1 landed while D tiles in
// flight; last D iterations are peeled with vmcnt(0) (round-2 race fix, generalized).
// Grid mapping (round 4): GROUP_M=8 grouped ordering + contiguous per-XCD chunks so each
// XCD's concurrent blocks span 8bm x <=8bn -> per-K-step slice set ~200 KB fits 4MB L2.
template <int BN, int WM, int WN, int RING, class Epi>
__global__ __launch_bounds__(512, RING == 3 ? 4 : 2)
void gemm256(const bf16* __restrict__ A, int lda,
             const bf16* __restrict__ Bm, int ldb,
             int Kd, int GM, Epi epi) {
  constexpr int BM = 256;
  constexpr int FM = BM / WM / 16;
  constexpr int FN = BN / WN / 16;
  constexpr int ACALLS = 2;          // 256 rows * 64B / (512 thr * 16B)
  constexpr int BCALLS = BN / 128;
  constexpr int L = ACALLS + BCALLS; // vmem instrs per K-tile per thread
  constexpr int D = RING - 1;        // prefetch depth
  constexpr int W = (D - 1) * L;     // steady-state vmcnt
  constexpr int SLOTA = BM * 64;     // bytes per A K-tile (BK=32 -> 64B rows)
  constexpr int SLOTB = BN * 64;
  constexpr int SLOT = SLOTA + SLOTB;
  __shared__ __align__(16) char lds[RING * SLOT];

  const int tid = threadIdx.x;
  const int lane = tid & 63;
  const int wid = tid >> 6;
  const int l15 = lane & 15, lq = lane >> 4;
  const int wr = wid / WN, wc = wid % WN;

  // per-XCD contiguous chunk (nwg % 8 == 0 for all our launches)
  const int nwg = gridDim.x;
  const int xcd = blockIdx.x & 7, loc = blockIdx.x >> 3;
  const int wg = xcd * (nwg >> 3) + loc;
  // grouped mapping: 8 bm fastest, then bn
  const int GN = nwg / GM;
  const int per = 8 * GN;
  const int g = wg / per, r = wg % per;
  const int bm = g * 8 + (r & 7);
  const int bn = r >> 3;

  const bf16* Abase = A + (int64_t)bm * BM * lda;
  const bf16* Bbase = Bm + (int64_t)bn * BN * ldb;

  // staging: LDS linear chunk -> pre-swizzled global source
  const bf16* srcA[ACALLS];
  int dstA[ACALLS];
#pragma unroll
  for (int c2 = 0; c2 < ACALLS; ++c2) {
    const int chunk = c2 * 512 + tid;
    const int row = chunk >> 2, pc = chunk & 3;
    const int lc = pc ^ ((row >> 1) & 3);
    srcA[c2] = Abase + (int64_t)row * lda + lc * 8;
    dstA[c2] = chunk * 16;
  }
  const bf16* srcB[BCALLS];
  int dstB[BCALLS];
#pragma unroll
  for (int c2 = 0; c2 < BCALLS; ++c2) {
    const int chunk = c2 * 512 + tid;
    const int row = chunk >> 2, pc = chunk & 3;
    const int lc = pc ^ ((row >> 1) & 3);
    srcB[c2] = Bbase + (int64_t)row * ldb + lc * 8;
    dstB[c2] = chunk * 16;
  }

  // fragment read offsets (swizzled)
  int offA[FM], offB[FN];
#pragma unroll
  for (int m = 0; m < FM; ++m) {
    const int row = wr * (BM / WM) + m * 16 + l15;
    offA[m] = row * 64 + (lq ^ ((row >> 1) & 3)) * 16;
  }
#pragma unroll
  for (int n = 0; n < FN; ++n) {
    const int row = wc * (BN / WN) + n * 16 + l15;
    offB[n] = SLOTA + row * 64 + (lq ^ ((row >> 1) & 3)) * 16;
  }

  const int KT = Kd >> 5;
  auto stage = [&](int t) {
    char* sb = lds + (size_t)(t % RING) * SLOT;
#pragma unroll
    for (int c2 = 0; c2 < ACALLS; ++c2)
      load_lds16(srcA[c2] + t * 32, sb + dstA[c2]);
#pragma unroll
    for (int c2 = 0; c2 < BCALLS; ++c2)
      load_lds16(srcB[c2] + t * 32, sb + SLOTA + dstB[c2]);
  };
  auto compute = [&](int t, f32x4 (&acc)[FM][FN]) {
    const char* sb = lds + (size_t)(t % RING) * SLOT;
    bf16x8 av[FM], bv[FN];
#pragma unroll
    for (int m = 0; m < FM; ++m) av[m] = *(const bf16x8*)(sb + offA[m]);
#pragma unroll
    for (int n = 0; n < FN; ++n) bv[n] = *(const bf16x8*)(sb + offB[n]);
    __builtin_amdgcn_s_setprio(1);
#pragma unroll
    for (int m = 0; m < FM; ++m)
#pragma unroll
      for (int n = 0; n < FN; ++n)
        acc[m][n] = __builtin_amdgcn_mfma_f32_16x16x32_bf16(av[m], bv[n], acc[m][n], 0, 0, 0);
    __builtin_amdgcn_s_setprio(0);
  };

  f32x4 acc[FM][FN] = {};

#pragma unroll
  for (int i = 0; i < D; ++i) stage(i);
  waitcnt_vm<W>();
  __builtin_amdgcn_s_barrier();
  __builtin_amdgcn_sched_barrier(0);

  // main loop: always D stage-groups in flight -> counted vmcnt proves tile t+1 landed
  for (int t = 0; t < KT - D; ++t) {
    stage(t + D);
    compute(t, acc);
    waitcnt_vm<W>();
    __builtin_amdgcn_s_barrier();
    __builtin_amdgcn_sched_barrier(0);
  }
  // peeled tail: no new stages in flight, counted vmcnt would be a no-op -> full drain
  for (int t = KT - D; t < KT; ++t) {
    compute(t, acc);
    waitcnt_vm<0>();
    __builtin_amdgcn_s_barrier();
    __builtin_amdgcn_sched_barrier(0);
  }

#pragma unroll
  for (int m = 0; m < FM; ++m) {
    const int r0 = bm * BM + wr * (BM / WM) + m * 16 + lq * 4;
#pragma unroll
    for (int n = 0; n < FN; ++n) {
      const int c1 = bn * BN + wc * (BN / WN) + n * 16 + l15;
#pragma unroll
      for (int j = 0; j < 4; ++j) epi(r0 + j, c1, acc[m][n][j]);
    }
  }
}

// ------------- old 128x128 (BK=32) core, kept for attention GEMMs -------------
template <class Epi, bool KLIMIT>
__device__ __forceinline__ void gemm_core(const bf16* __restrict__ A, int lda,
                                          const bf16* __restrict__ Bm, int ldb,
                                          int Kd, const Epi& epi) {
  __shared__ __align__(16) bf16 sA[128 * 32];
  __shared__ __align__(16) bf16 sB[128 * 32];
  const int tid = threadIdx.x;
  const int lane = tid & 63;
  const int wid = tid >> 6;
  const int wr = wid >> 1, wc = wid & 1;
  const int bm = blockIdx.y, bn = blockIdx.x;
  const int l15 = lane & 15;
  const int kh = (lane >> 4) * 8;

  f32x4 acc[4][4] = {};
  int ktiles = Kd >> 5;
  if (KLIMIT) {
    int lim = ((bm + 1) * 128) >> 5;
    if (lim < ktiles) ktiles = lim;
  }
  const bf16* Abase = A + (int64_t)bm * 128 * lda;
  const bf16* Bbase = Bm + (int64_t)bn * 128 * ldb;

  for (int kt = 0; kt < ktiles; ++kt) {
#pragma unroll
    for (int i = 0; i < 2; ++i) {
      int c = i * 256 + tid;
      int row = c >> 2;
      int off = (c & 3) * 8;
      load_lds16(Abase + (int64_t)row * lda + kt * 32 + off, &sA[c * 8]);
      load_lds16(Bbase + (int64_t)row * ldb + kt * 32 + off, &sB[c * 8]);
    }
    __syncthreads();
    bf16x8 av[4], bv[4];
#pragma unroll
    for (int m = 0; m < 4; ++m) av[m] = *(const bf16x8*)&sA[(wr * 64 + m * 16 + l15) * 32 + kh];
#pragma unroll
    for (int n = 0; n < 4; ++n) bv[n] = *(const bf16x8*)&sB[(wc * 64 + n * 16 + l15) * 32 + kh];
#pragma unroll
    for (int m = 0; m < 4; ++m)
#pragma unroll
      for (int n = 0; n < 4; ++n)
        acc[m][n] = __builtin_amdgcn_mfma_f32_16x16x32_bf16(av[m], bv[n], acc[m][n], 0, 0, 0);
    __syncthreads();
  }

#pragma unroll
  for (int m = 0; m < 4; ++m) {
    const int r0 = bm * 128 + wr * 64 + m * 16 + (lane >> 4) * 4;
#pragma unroll
    for (int n = 0; n < 4; ++n) {
      const int c1 = bn * 128 + wc * 64 + n * 16 + l15;
#pragma unroll
      for (int j = 0; j < 4; ++j) epi(r0 + j, c1, acc[m][n][j]);
    }
  }
}

// ---------------- epilogues ----------------
struct EpiQKV {
  bf16* out; const float* bias;
  __device__ void operator()(int r, int c, float v) const {
    out[(int64_t)r * QKVW + c] = (bf16)(v + bias[c]);
  }
};
struct EpiS {
  bf16* S;
  __device__ void operator()(int r, int c, float v) const {
    S[(int64_t)r * cK + c] = (bf16)v;
  }
};
struct EpiPV {
  bf16* out; int coff;
  __device__ void operator()(int r, int c, float v) const {
    out[(int64_t)r * (cH * cHD) + coff + c] = (bf16)v;
  }
};
struct EpiOProj {
  float* x; const float* hidden; const int* topk;
  __device__ void operator()(int r, int c, float v) const {
    int b = r >> 10;
    int t = topk[r];
    x[(int64_t)r * cD + c] = v + hidden[((int64_t)b * cT + t) * cD + c];
  }
};
struct EpiBF16Out {
  bf16* out; int ldc;
  __device__ void operator()(int r, int c, float v) const {
    out[(int64_t)r * ldc + c] = (bf16)v;
  }
};
struct EpiUp {  // act = silu(gate) * up, in place over gate buffer
  bf16* act;
  __device__ void operator()(int r, int c, float v) const {
    int64_t o = (int64_t)r * cFF + c;
    float g = (float)act[o];
    float s = g / (1.f + __expf(-g));
    act[o] = (bf16)(s * v);
  }
};
struct EpiDown {  // x2 = x + acc; upd = sel + (x2-sel)*gate; scatter to d_out
  float* out; const float* x; const float* hidden; const int* topk; const float* gating;
  __device__ void operator()(int r, int c, float v) const {
    int b = r >> 10;
    int t = topk[r];
    float x2 = v + x[(int64_t)r * cD + c];
    int64_t ho = ((int64_t)b * cT + t) * cD + c;
    float sel = hidden[ho];
    out[ho] = sel + (x2 - sel) * gating[r];
  }
};

// ---------------- attention GEMM kernels (old core) ----------------
__global__ __launch_bounds__(256) void gemm_s_kernel(const bf16* __restrict__ qkv_b,
                                                     bf16* __restrict__ Sb) {
  if (blockIdx.x > blockIdx.y) return;  // causal: only lower-triangular tiles
  const int h = blockIdx.z;
  EpiS epi{Sb + (int64_t)h * cK * cK};
  gemm_core<EpiS, false>(qkv_b + h * cHD, QKVW,
                         qkv_b + cH * cHD + (h >> 2) * cHD, QKVW, cHD, epi);
}

__global__ __launch_bounds__(256) void gemm_pv_kernel(const bf16* __restrict__ Pb,
                                                      const bf16* __restrict__ Vt_b,
                                                      bf16* __restrict__ outb) {
  const int h = blockIdx.z;
  EpiPV epi{outb, h * cHD};
  gemm_core<EpiPV, true>(Pb + (int64_t)h * cK * cK, cK,
                         Vt_b + (int64_t)(h >> 2) * cHD * cK, cK, cK, epi);
}

// ---------------- elementwise / staging kernels ----------------
__global__ void copy_f4(const float4* __restrict__ s, float4* __restrict__ d, int64_t n) {
  int64_t i = (int64_t)blockIdx.x * blockDim.x + threadIdx.x;
  const int64_t st = (int64_t)gridDim.x * blockDim.x;
  for (; i < n; i += st) d[i] = s[i];
}

// fp32 (R,C) -> bf16 (C,R) with column offset into a concat buffer
__global__ void wconv(const float* __restrict__ src, bf16* __restrict__ dst,
                      int R, int C, int coff, int ldd) {
  __shared__ float t[32][33];
  const int c0 = blockIdx.x * 32, r0 = blockIdx.y * 32;
  for (int rr = threadIdx.y; rr < 32; rr += 8)
    t[rr][threadIdx.x] = src[(int64_t)(r0 + rr) * C + c0 + threadIdx.x];
  __syncthreads();
  for (int rr = threadIdx.y; rr < 32; rr += 8)
    dst[(int64_t)(c0 + rr + coff) * ldd + r0 + threadIdx.x] = (bf16)t[threadIdx.x][rr];
}

__global__ void biascat(const float* __restrict__ bq, const float* __restrict__ bk,
                        const float* __restrict__ bv, float* __restrict__ o) {
  int i = blockIdx.x * 256 + threadIdx.x;
  if (i < QKVW) o[i] = (i < 2048) ? bq[i] : (i < 2560 ? bk[i - 2048] : bv[i - 2560]);
}

// gather (topk!=null) or direct rows (topk==null) + RMSNorm -> bf16
__global__ void rmsnorm_rows(const float* __restrict__ base, const int* __restrict__ topk,
                             const float* __restrict__ w, bf16* __restrict__ out) {
  const int r = blockIdx.x;
  const float* src;
  if (topk) {
    int t = topk[r];
    src = base + ((int64_t)(r >> 10) * cT + t) * cD;
  } else {
    src = base + (int64_t)r * cD;
  }
  const int tid = threadIdx.x;
  const float4* s4 = (const float4*)src;
  float4 a = s4[tid * 2], b = s4[tid * 2 + 1];
  float ss = a.x * a.x + a.y * a.y + a.z * a.z + a.w * a.w +
             b.x * b.x + b.y * b.y + b.z * b.z + b.w * b.w;
  float tot = blk_reduce<0>(ss);
  float sc = rsqrtf(tot * (1.f / cD) + 1e-6f);
  bf16* o = out + (int64_t)r * cD;
  const int d0 = tid * 8;
  o[d0 + 0] = (bf16)(a.x * sc * w[d0 + 0]);
  o[d0 + 1] = (bf16)(a.y * sc * w[d0 + 1]);
  o[d0 + 2] = (bf16)(a.z * sc * w[d0 + 2]);
  o[d0 + 3] = (bf16)(a.w * sc * w[d0 + 3]);
  o[d0 + 4] = (bf16)(b.x * sc * w[d0 + 4]);
  o[d0 + 5] = (bf16)(b.y * sc * w[d0 + 5]);
  o[d0 + 6] = (bf16)(b.z * sc * w[d0 + 6]);
  o[d0 + 7] = (bf16)(b.w * sc * w[d0 + 7]);
}

__global__ void rope_kernel(bf16* __restrict__ qkv, const float* __restrict__ cosb,
                            const float* __restrict__ sinb, const int* __restrict__ topk) {
  const int r = blockIdx.x;  // b*K + k
  const int b = r >> 10;
  const int t = topk[r];
  const float* cr = cosb + ((int64_t)b * cT + t) * cHD;
  const float* sr = sinb + ((int64_t)b * cT + t) * cHD;
  bf16* rowq = qkv + (int64_t)r * QKVW;
  for (int p = threadIdx.x; p < (cH + cKVH) * 64; p += 256) {
    int hh = p >> 6, d = p & 63;
    bf16* base = (hh < cH) ? (rowq + hh * cHD) : (rowq + cH * cHD + (hh - cH) * cHD);
    float x1 = (float)base[d], x2 = (float)base[d + 64];
    float c1 = cr[d], s1 = sr[d], c2 = cr[d + 64], s2 = sr[d + 64];
    base[d] = (bf16)(x1 * c1 - x2 * s1);
    base[d + 64] = (bf16)(x2 * c2 + x1 * s2);
  }
}

// v-part of qkv -> Vt (B,KVH,HD,K) bf16
__global__ void vtrans(const bf16* __restrict__ qkv, bf16* __restrict__ Vt) {
  __shared__ bf16 t[32][33];
  const int bz = blockIdx.z, b = bz >> 2, kv = bz & 3;
  const int k0 = blockIdx.x * 32, d0 = blockIdx.y * 32;
  for (int rr = threadIdx.y; rr < 32; rr += 8)
    t[rr][threadIdx.x] =
        qkv[(int64_t)(b * cK + k0 + rr) * QKVW + cH * cHD + cKVH * cHD + kv * cHD + d0 + threadIdx.x];
  __syncthreads();
  for (int rr = threadIdx.y; rr < 32; rr += 8)
    Vt[((int64_t)(b * cKVH + kv) * cHD + d0 + rr) * cK + k0 + threadIdx.x] = t[threadIdx.x][rr];
}

// causal row softmax over S (16,1024,1024) bf16, in place, zero-pad to 128 tile
__global__ void softmax_causal(bf16* __restrict__ S) {
  const int i = blockIdx.x, h = blockIdx.y;
  bf16* row = S + ((int64_t)h * cK + i) * cK;
  const int len = i + 1;
  const float scale = 0.08838834764831845f;  // 1/sqrt(128)
  const int tid = threadIdx.x;
  float vals[4];
  int cnt = 0;
  float m = -3.0e38f;
  for (int j = tid; j < len; j += 256) {
    float v = (float)row[j] * scale;
    vals[cnt++] = v;
    m = fmaxf(m, v);
  }
  float M = blk_reduce<1>(m);
  float s = 0.f;
  for (int q = 0; q < cnt; ++q) {
    float e = __expf(vals[q] - M);
    vals[q] = e;
    s += e;
  }
  float SUM = blk_reduce<0>(s);
  float inv = 1.f / SUM;
  int q2 = 0;
  for (int j = tid; j < len; j += 256) row[j] = (bf16)(vals[q2++] * inv);
  const int pad = ((i >> 7) + 1) << 7;
  for (int j = len + tid; j < pad; j += 256) row[j] = (bf16)0.f;
}

}  // namespace

extern "C" void kernel_launch(void* const* d_in, const int* in_sizes, int n_in,
                              void* d_out, int out_size, void* d_ws, size_t ws_size,
                              hipStream_t stream) {
  const float* hidden = (const float*)d_in[0];
  const int* topk = (const int*)d_in[1];
  const float* gating = (const float*)d_in[2];
  const float* cosb = (const float*)d_in[3];
  const float* sinb = (const float*)d_in[4];
  const float* Wq = (const float*)d_in[5];
  const float* bq = (const float*)d_in[6];
  const float* Wk = (const float*)d_in[7];
  const float* bk = (const float*)d_in[8];
  const float* Wv = (const float*)d_in[9];
  const float* bv = (const float*)d_in[10];
  const float* Wo = (const float*)d_in[11];
  const float* wg = (const float*)d_in[12];
  const float* wu = (const float*)d_in[13];
  const float* wd = (const float*)d_in[14];
  const float* ln1 = (const float*)d_in[15];
  const float* ln2 = (const float*)d_in[16];
  float* out = (float*)d_out;
  (void)in_sizes; (void)n_in; (void)out_size; (void)ws_size;

  char* ws = (char*)d_ws;
  size_t off = 0;
  auto alloc = [&](size_t bytes) {
    char* p = ws + off;
    off += (bytes + 255) & ~(size_t)255;
    return p;
  };
  bf16* wt_qkv = (bf16*)alloc((size_t)QKVW * cD * 2);
  bf16* wt_o = (bf16*)alloc((size_t)cD * cD * 2);
  bf16* wt_g = (bf16*)alloc((size_t)cFF * cD * 2);
  bf16* wt_u = (bf16*)alloc((size_t)cFF * cD * 2);
  bf16* wt_d = (bf16*)alloc((size_t)cD * cFF * 2);
  float* bias_cat = (float*)alloc((size_t)QKVW * 4);
  bf16* hbuf = (bf16*)alloc((size_t)cM * cD * 2);
  bf16* qkv = (bf16*)alloc((size_t)cM * QKVW * 2);
  bf16* vt = (bf16*)alloc((size_t)cB * cKVH * cHD * cK * 2);
  bf16* attnout = (bf16*)alloc((size_t)cM * cD * 2);
  float* xbuf = (float*)alloc((size_t)cM * cD * 4);
  bf16* actbuf = (bf16*)alloc((size_t)cM * cFF * 2);
  bf16* sbuf = (bf16*)alloc((size_t)cH * cK * cK * 2);

  // d_out = hidden_states (scatter overwrites selected rows later)
  copy_f4<<<2048, 256, 0, stream>>>((const float4*)hidden, (float4*)out,
                                    (int64_t)cB * cT * cD / 4);

  const dim3 tb(32, 8);
  wconv<<<dim3(cD / 32, cD / 32), tb, 0, stream>>>(Wq, wt_qkv, cD, cD, 0, cD);
  wconv<<<dim3(512 / 32, cD / 32), tb, 0, stream>>>(Wk, wt_qkv, cD, 512, 2048, cD);
  wconv<<<dim3(512 / 32, cD / 32), tb, 0, stream>>>(Wv, wt_qkv, cD, 512, 2560, cD);
  wconv<<<dim3(cD / 32, cD / 32), tb, 0, stream>>>(Wo, wt_o, cD, cD, 0, cD);
  wconv<<<dim3(cFF / 32, cD / 32), tb, 0, stream>>>(wg, wt_g, cD, cFF, 0, cD);
  wconv<<<dim3(cFF / 32, cD / 32), tb, 0, stream>>>(wu, wt_u, cD, cFF, 0, cD);
  wconv<<<dim3(cD / 32, cFF / 32), tb, 0, stream>>>(wd, wt_d, cFF, cD, 0, cFF);
  biascat<<<(QKVW + 255) / 256, 256, 0, stream>>>(bq, bk, bv, bias_cat);

  // gather + rmsnorm1
  rmsnorm_rows<<<cM, 256, 0, stream>>>(hidden, topk, ln1, hbuf);
  // qkv projection (+bias)
  gemm256<256, 2, 4, 4, EpiQKV><<<16 * (QKVW / 256), 512, 0, stream>>>(
      hbuf, cD, wt_qkv, cD, cD, 16, EpiQKV{qkv, bias_cat});
  rope_kernel<<<cM, 256, 0, stream>>>(qkv, cosb, sinb, topk);
  vtrans<<<dim3(cK / 32, cHD / 32, cB * cKVH), tb, 0, stream>>>(qkv, vt);

  for (int b = 0; b < cB; ++b) {
    const bf16* qkv_b = qkv + (int64_t)b * cK * QKVW;
    gemm_s_kernel<<<dim3(cK / 128, cK / 128, cH), 256, 0, stream>>>(qkv_b, sbuf);
    softmax_causal<<<dim3(cK, cH), 256, 0, stream>>>(sbuf);
    gemm_pv_kernel<<<dim3(cHD / 128, cK / 128, cH), 256, 0, stream>>>(
        sbuf, vt + (int64_t)b * cKVH * cHD * cK, attnout + (int64_t)b * cK * cD);
  }

  // o-proj + gathered residual -> x (fp32)
  gemm256<128, 4, 2, 3, EpiOProj><<<16 * (cD / 128), 512, 0, stream>>>(
      attnout, cD, wt_o, cD, cD, 16, EpiOProj{xbuf, hidden, topk});
  // rmsnorm2
  rmsnorm_rows<<<cM, 256, 0, stream>>>(xbuf, nullptr, ln2, hbuf);
  // gate, then act = silu(gate)*up in place
  gemm256<256, 2, 4, 4, EpiBF16Out><<<16 * (cFF / 256), 512, 0, stream>>>(
      hbuf, cD, wt_g, cD, cD, 16, EpiBF16Out{actbuf, cFF});
  gemm256<256, 2, 4, 4, EpiUp><<<16 * (cFF / 256), 512, 0, stream>>>(
      hbuf, cD, wt_u, cD, cD, 16, EpiUp{actbuf});
  // down + residual + gating + scatter into d_out
  gemm256<128, 4, 2, 3, EpiDown><<<16 * (cD / 128), 512, 0, stream>>>(
      actbuf, cFF, wt_d, cFF, cFF, 16, EpiDown{out, xbuf, hidden, topk, gating});
}

// Round 6
// 897.370 us; speedup vs baseline: 1.4376x; 1.1873x over previous
//
#include <hip/hip_runtime.h>
#include <stdint.h>

typedef __bf16 bf16;
typedef __attribute__((ext_vector_type(8))) __bf16 bf16x8;
typedef __attribute__((ext_vector_type(4))) float f32x4;

namespace {

constexpr int cB = 4, cT = 4096, cD = 2048, cK = 1024, cH = 16, cKVH = 4, cHD = 128, cFF = 8192;
constexpr int cM = cB * cK;                 // 4096 gathered rows
constexpr int QKVW = cH * cHD + 2 * cKVH * cHD; // 3072

__device__ __forceinline__ void load_lds16(const void* g, void* l) {
  __builtin_amdgcn_global_load_lds((const __attribute__((address_space(1))) void*)g,
                                   (__attribute__((address_space(3))) void*)l, 16, 0, 0);
}

template <int N>
__device__ __forceinline__ void waitcnt_vm() {
  if constexpr (N == 0) asm volatile("s_waitcnt vmcnt(0)" ::: "memory");
  else if constexpr (N == 4) asm volatile("s_waitcnt vmcnt(4)" ::: "memory");
  else if constexpr (N == 6) asm volatile("s_waitcnt vmcnt(6)" ::: "memory");
  else if constexpr (N == 8) asm volatile("s_waitcnt vmcnt(8)" ::: "memory");
  else if constexpr (N == 9) asm volatile("s_waitcnt vmcnt(9)" ::: "memory");
  else if constexpr (N == 12) asm volatile("s_waitcnt vmcnt(12)" ::: "memory");
  else static_assert(N == 0, "unsupported vmcnt literal");
}

// ---------------- block reduce (256 threads = 4 waves) ----------------
template <int OP>  // 0 = sum, 1 = max
__device__ __forceinline__ float blk_reduce(float v) {
  __shared__ float sm[5];
  const int tid = threadIdx.x, lane = tid & 63, wid = tid >> 6;
#pragma unroll
  for (int o = 32; o; o >>= 1) {
    float o2 = __shfl_down(v, o, 64);
    v = OP ? fmaxf(v, o2) : v + o2;
  }
  if (lane == 0) sm[wid] = v;
  __syncthreads();
  if (tid == 0) {
    float r = sm[0];
#pragma unroll
    for (int i = 1; i < 4; ++i) r = OP ? fmaxf(r, sm[i]) : r + sm[i];
    sm[4] = r;
  }
  __syncthreads();
  float r = sm[4];
  __syncthreads();
  return r;
}

// ================= deep-pipelined 256-row MFMA GEMM: C = A * B^T =================
// A: M x Kd row-major (lda), B: N x Kd row-major (ldb). BM=256, BK=32.
// 8 waves (512 thr), WM x WN wave grid, RING-slot LDS ring (prefetch depth D=RING-1),
// counted vmcnt, raw barriers, XOR-swizzled LDS (pre-swizzled global src + swizzled read).
// vmcnt ledger: end of main iter t waits (D-1)*L -> tile t+1 landed while D tiles in
// flight; last D iterations are peeled with vmcnt(0) (round-2 race fix, generalized).
// BN=128 GEMMs are grid-limited to 1 block/CU, so RING=5 (120 KB LDS) spends idle LDS
// on depth: D=4 -> 3-iteration latency cover ~ HBM latency.
template <int BN, int WM, int WN, int RING, class Epi>
__global__ __launch_bounds__(512, 2)
void gemm256(const bf16* __restrict__ A, int lda,
             const bf16* __restrict__ Bm, int ldb,
             int Kd, int GM, Epi epi) {
  constexpr int BM = 256;
  constexpr int FM = BM / WM / 16;
  constexpr int FN = BN / WN / 16;
  constexpr int ACALLS = 2;          // 256 rows * 64B / (512 thr * 16B)
  constexpr int BCALLS = BN / 128;
  constexpr int L = ACALLS + BCALLS; // vmem instrs per K-tile per thread
  constexpr int D = RING - 1;        // prefetch depth
  constexpr int W = (D - 1) * L;     // steady-state vmcnt
  constexpr int SLOTA = BM * 64;     // bytes per A K-tile (BK=32 -> 64B rows)
  constexpr int SLOTB = BN * 64;
  constexpr int SLOT = SLOTA + SLOTB;
  __shared__ __align__(16) char lds[RING * SLOT];

  const int tid = threadIdx.x;
  const int lane = tid & 63;
  const int wid = tid >> 6;
  const int l15 = lane & 15, lq = lane >> 4;
  const int wr = wid / WN, wc = wid % WN;

  // per-XCD contiguous chunk (nwg % 8 == 0 for all our launches)
  const int nwg = gridDim.x;
  const int xcd = blockIdx.x & 7, loc = blockIdx.x >> 3;
  const int wg = xcd * (nwg >> 3) + loc;
  // grouped mapping: 8 bm fastest, then bn
  const int GN = nwg / GM;
  const int per = 8 * GN;
  const int g = wg / per, r = wg % per;
  const int bm = g * 8 + (r & 7);
  const int bn = r >> 3;

  const bf16* Abase = A + (int64_t)bm * BM * lda;
  const bf16* Bbase = Bm + (int64_t)bn * BN * ldb;

  // staging: LDS linear chunk -> pre-swizzled global source
  const bf16* srcA[ACALLS];
  int dstA[ACALLS];
#pragma unroll
  for (int c2 = 0; c2 < ACALLS; ++c2) {
    const int chunk = c2 * 512 + tid;
    const int row = chunk >> 2, pc = chunk & 3;
    const int lc = pc ^ ((row >> 1) & 3);
    srcA[c2] = Abase + (int64_t)row * lda + lc * 8;
    dstA[c2] = chunk * 16;
  }
  const bf16* srcB[BCALLS];
  int dstB[BCALLS];
#pragma unroll
  for (int c2 = 0; c2 < BCALLS; ++c2) {
    const int chunk = c2 * 512 + tid;
    const int row = chunk >> 2, pc = chunk & 3;
    const int lc = pc ^ ((row >> 1) & 3);
    srcB[c2] = Bbase + (int64_t)row * ldb + lc * 8;
    dstB[c2] = chunk * 16;
  }

  // fragment read offsets (swizzled)
  int offA[FM], offB[FN];
#pragma unroll
  for (int m = 0; m < FM; ++m) {
    const int row = wr * (BM / WM) + m * 16 + l15;
    offA[m] = row * 64 + (lq ^ ((row >> 1) & 3)) * 16;
  }
#pragma unroll
  for (int n = 0; n < FN; ++n) {
    const int row = wc * (BN / WN) + n * 16 + l15;
    offB[n] = SLOTA + row * 64 + (lq ^ ((row >> 1) & 3)) * 16;
  }

  const int KT = Kd >> 5;
  auto stage = [&](int t) {
    char* sb = lds + (size_t)(t % RING) * SLOT;
#pragma unroll
    for (int c2 = 0; c2 < ACALLS; ++c2)
      load_lds16(srcA[c2] + t * 32, sb + dstA[c2]);
#pragma unroll
    for (int c2 = 0; c2 < BCALLS; ++c2)
      load_lds16(srcB[c2] + t * 32, sb + SLOTA + dstB[c2]);
  };
  auto compute = [&](int t, f32x4 (&acc)[FM][FN]) {
    const char* sb = lds + (size_t)(t % RING) * SLOT;
    bf16x8 av[FM], bv[FN];
#pragma unroll
    for (int m = 0; m < FM; ++m) av[m] = *(const bf16x8*)(sb + offA[m]);
#pragma unroll
    for (int n = 0; n < FN; ++n) bv[n] = *(const bf16x8*)(sb + offB[n]);
    __builtin_amdgcn_s_setprio(1);
#pragma unroll
    for (int m = 0; m < FM; ++m)
#pragma unroll
      for (int n = 0; n < FN; ++n)
        acc[m][n] = __builtin_amdgcn_mfma_f32_16x16x32_bf16(av[m], bv[n], acc[m][n], 0, 0, 0);
    __builtin_amdgcn_s_setprio(0);
  };

  f32x4 acc[FM][FN] = {};

#pragma unroll
  for (int i = 0; i < D; ++i) stage(i);
  waitcnt_vm<W>();
  __builtin_amdgcn_s_barrier();
  __builtin_amdgcn_sched_barrier(0);

  // main loop: always D stage-groups in flight -> counted vmcnt proves tile t+1 landed
  for (int t = 0; t < KT - D; ++t) {
    stage(t + D);
    compute(t, acc);
    waitcnt_vm<W>();
    __builtin_amdgcn_s_barrier();
    __builtin_amdgcn_sched_barrier(0);
  }
  // peeled tail: no new stages in flight, counted vmcnt would be a no-op -> full drain
  for (int t = KT - D; t < KT; ++t) {
    compute(t, acc);
    waitcnt_vm<0>();
    __builtin_amdgcn_s_barrier();
    __builtin_amdgcn_sched_barrier(0);
  }

#pragma unroll
  for (int m = 0; m < FM; ++m) {
    const int r0 = bm * BM + wr * (BM / WM) + m * 16 + lq * 4;
#pragma unroll
    for (int n = 0; n < FN; ++n) {
      const int c1 = bn * BN + wc * (BN / WN) + n * 16 + l15;
#pragma unroll
      for (int j = 0; j < 4; ++j) epi(r0 + j, c1, acc[m][n][j]);
    }
  }
}

// ---------------- epilogues ----------------
struct EpiQKV {
  bf16* out; const float* bias;
  __device__ void operator()(int r, int c, float v) const {
    out[(int64_t)r * QKVW + c] = (bf16)(v + bias[c]);
  }
};
struct EpiOProj {
  float* x; const float* hidden; const int* topk;
  __device__ void operator()(int r, int c, float v) const {
    int b = r >> 10;
    int t = topk[r];
    x[(int64_t)r * cD + c] = v + hidden[((int64_t)b * cT + t) * cD + c];
  }
};
struct EpiBF16Out {
  bf16* out; int ldc;
  __device__ void operator()(int r, int c, float v) const {
    out[(int64_t)r * ldc + c] = (bf16)v;
  }
};
struct EpiUp {  // act = silu(gate) * up, in place over gate buffer
  bf16* act;
  __device__ void operator()(int r, int c, float v) const {
    int64_t o = (int64_t)r * cFF + c;
    float g = (float)act[o];
    float s = g / (1.f + __expf(-g));
    act[o] = (bf16)(s * v);
  }
};
struct EpiDown {  // x2 = x + acc; upd = sel + (x2-sel)*gate; scatter to d_out
  float* out; const float* x; const float* hidden; const int* topk; const float* gating;
  __device__ void operator()(int r, int c, float v) const {
    int b = r >> 10;
    int t = topk[r];
    float x2 = v + x[(int64_t)r * cD + c];
    int64_t ho = ((int64_t)b * cT + t) * cD + c;
    float sel = hidden[ho];
    out[ho] = sel + (x2 - sel) * gating[r];
  }
};

// ================= fused flash attention =================
// grid (16 qtiles of 64 rows, 16 heads, 4 batches), 256 thr = 4 waves.
// ROUND-6 FIX: each wave owns 16 FULL rows x all 128 kv-cols (wid = row block), so the
// online-softmax row reduce (shfl_xor over l15) spans the complete row, P rows are
// written+read by the same wave, and l_run is the true row sum. (Round-5 bug: 2x2 wave
// grid split rows across waves -> two inconsistent row-maxes per row.)
// LDS: sK 32K (Q staged here first) | sP 16K | sV 32K = 80 KB -> 2 blocks/CU.
// All LDS tiles XOR-swizzled (16B chunk ^ row&15) via pre-swizzled global src.
// __syncthreads() everywhere (drains vmcnt+lgkmcnt -> no Q-read/staging race).
__global__ __launch_bounds__(256, 2) void flash_attn(const bf16* __restrict__ qkv,
                                                     const bf16* __restrict__ vt,
                                                     bf16* __restrict__ outb) {
  constexpr int QB = 64, KVB = 128;
  __shared__ __align__(16) char lds[81920];
  char* sK = lds;            // 32 KB (also Q staging)
  char* sP = lds + 32768;    // 16 KB
  char* sV = lds + 49152;    // 32 KB

  const int qt = blockIdx.x, h = blockIdx.y, b = blockIdx.z;
  const int kvh = h >> 2;
  const int qlo = qt * QB;
  const int tid = threadIdx.x, lane = tid & 63, wid = tid >> 6;
  const int l15 = lane & 15, lq = lane >> 4;
  const int wid16 = wid * 16;  // this wave's 16-row block

  const bf16* qbase = qkv + (int64_t)(b * cK + qlo) * QKVW + h * cHD;
  const bf16* kbase = qkv + (int64_t)(b * cK) * QKVW + cH * cHD + kvh * cHD;
  const bf16* vtbase = vt + (int64_t)(b * cKVH + kvh) * cHD * cK;

  // ---- stage Q (64 rows x 256B) into sK region, read frags to regs ----
#pragma unroll
  for (int c2 = 0; c2 < 4; ++c2) {
    int chunk = c2 * 256 + tid;
    int row = chunk >> 4, c16 = chunk & 15;
    load_lds16(qbase + (int64_t)row * QKVW + (c16 ^ (row & 15)) * 8, sK + chunk * 16);
  }
  __syncthreads();
  bf16x8 qf[4];
  {
    const int row = wid16 + l15;
#pragma unroll
    for (int kt = 0; kt < 4; ++kt)
      qf[kt] = *(const bf16x8*)(sK + row * 256 + (((kt * 4 + lq) ^ (row & 15)) * 16));
  }
  __syncthreads();  // all Q reads complete before K staging overwrites sK

  f32x4 oacc[8] = {};
  float m_run[4], l_run[4];
#pragma unroll
  for (int j = 0; j < 4; ++j) { m_run[j] = -3.0e38f; l_run[j] = 0.f; }

  const int jmax = (qlo + QB - 1) >> 7;
  const float sl2e = 0.08838834764831845f * 1.44269504088896f;  // scale * log2(e)

  for (int jj = 0; jj <= jmax; ++jj) {
    // stage K tile (128 rows x 256B) and Vt tile (128 d-rows x 256B)
#pragma unroll
    for (int c2 = 0; c2 < 8; ++c2) {
      int chunk = c2 * 256 + tid;
      int row = chunk >> 4, c16 = chunk & 15;
      int cs = (c16 ^ (row & 15)) * 8;
      load_lds16(kbase + (int64_t)(jj * KVB + row) * QKVW + cs, sK + chunk * 16);
      load_lds16(vtbase + (int64_t)row * cK + jj * KVB + cs, sV + chunk * 16);
    }
    __syncthreads();

    // S = Q K^T : rows = this wave's 16 q-rows, cols = all 128 kv of this tile
    f32x4 sacc[8] = {};
#pragma unroll
    for (int kt = 0; kt < 4; ++kt) {
      bf16x8 bv[8];
#pragma unroll
      for (int n = 0; n < 8; ++n) {
        int rk = n * 16 + l15;
        bv[n] = *(const bf16x8*)(sK + rk * 256 + (((kt * 4 + lq) ^ (rk & 15)) * 16));
      }
#pragma unroll
      for (int n = 0; n < 8; ++n)
        sacc[n] = __builtin_amdgcn_mfma_f32_16x16x32_bf16(qf[kt], bv[n], sacc[n], 0, 0, 0);
    }

    // causal mask on diagonal tile
    if (jj == jmax) {
#pragma unroll
      for (int n = 0; n < 8; ++n)
#pragma unroll
        for (int j = 0; j < 4; ++j) {
          int qrow = qlo + wid16 + lq * 4 + j;
          int kcol = jj * KVB + n * 16 + l15;
          if (kcol > qrow) sacc[n][j] = -3.0e38f;
        }
    }

    // online softmax: lane owns rows (lq*4+j); full row = 8 n-frags x 16 l15 lanes
#pragma unroll
    for (int j = 0; j < 4; ++j) {
      float mx = sacc[0][j];
#pragma unroll
      for (int n = 1; n < 8; ++n) mx = fmaxf(mx, sacc[n][j]);
#pragma unroll
      for (int off = 1; off < 16; off <<= 1) mx = fmaxf(mx, __shfl_xor(mx, off, 64));
      float mnew = fmaxf(m_run[j], mx);
      float corr = exp2f((m_run[j] - mnew) * sl2e);
      m_run[j] = mnew;
      float ps = 0.f;
#pragma unroll
      for (int n = 0; n < 8; ++n) {
        float p = exp2f((sacc[n][j] - mnew) * sl2e);
        sacc[n][j] = p;
        ps += p;
      }
#pragma unroll
      for (int off = 1; off < 16; off <<= 1) ps += __shfl_xor(ps, off, 64);
      l_run[j] = l_run[j] * corr + ps;
#pragma unroll
      for (int n = 0; n < 8; ++n) oacc[n][j] *= corr;
    }

    // P -> LDS (bf16, swizzled); same wave writes and reads its own 16 rows
#pragma unroll
    for (int n = 0; n < 8; ++n)
#pragma unroll
      for (int j = 0; j < 4; ++j) {
        int row = wid16 + lq * 4 + j;
        int col = n * 16 + l15;
        int c16 = (col >> 3) ^ (row & 15);
        *(bf16*)(sP + row * 256 + c16 * 16 + (col & 7) * 2) = (bf16)sacc[n][j];
      }
    __syncthreads();

    // O += P @ Vt^T  (A = P own rows, B = Vt d-rows)
#pragma unroll
    for (int kt = 0; kt < 4; ++kt) {
      const int prow = wid16 + l15;
      bf16x8 av = *(const bf16x8*)(sP + prow * 256 + (((kt * 4 + lq) ^ (prow & 15)) * 16));
      bf16x8 bv[8];
#pragma unroll
      for (int n = 0; n < 8; ++n) {
        int rd = n * 16 + l15;
        bv[n] = *(const bf16x8*)(sV + rd * 256 + (((kt * 4 + lq) ^ (rd & 15)) * 16));
      }
#pragma unroll
      for (int n = 0; n < 8; ++n)
        oacc[n] = __builtin_amdgcn_mfma_f32_16x16x32_bf16(av, bv[n], oacc[n], 0, 0, 0);
    }
    __syncthreads();  // PV reads of sP/sV done before next stage overwrites
  }

  // O / l -> attnout
#pragma unroll
  for (int j = 0; j < 4; ++j) {
    int row = qlo + wid16 + lq * 4 + j;
    float inv = 1.f / l_run[j];
#pragma unroll
    for (int n = 0; n < 8; ++n) {
      int col = h * cHD + n * 16 + l15;
      outb[((int64_t)b * cK + row) * cD + col] = (bf16)(oacc[n][j] * inv);
    }
  }
}

// ---------------- elementwise / staging kernels ----------------
__global__ void copy_f4(const float4* __restrict__ s, float4* __restrict__ d, int64_t n) {
  int64_t i = (int64_t)blockIdx.x * blockDim.x + threadIdx.x;
  const int64_t st = (int64_t)gridDim.x * blockDim.x;
  for (; i < n; i += st) d[i] = s[i];
}

// fp32 (R,C) -> bf16 (C,R) with column offset into a concat buffer
__global__ void wconv(const float* __restrict__ src, bf16* __restrict__ dst,
                      int R, int C, int coff, int ldd) {
  __shared__ float t[32][33];
  const int c0 = blockIdx.x * 32, r0 = blockIdx.y * 32;
  for (int rr = threadIdx.y; rr < 32; rr += 8)
    t[rr][threadIdx.x] = src[(int64_t)(r0 + rr) * C + c0 + threadIdx.x];
  __syncthreads();
  for (int rr = threadIdx.y; rr < 32; rr += 8)
    dst[(int64_t)(c0 + rr + coff) * ldd + r0 + threadIdx.x] = (bf16)t[threadIdx.x][rr];
}

__global__ void biascat(const float* __restrict__ bq, const float* __restrict__ bk,
                        const float* __restrict__ bv, float* __restrict__ o) {
  int i = blockIdx.x * 256 + threadIdx.x;
  if (i < QKVW) o[i] = (i < 2048) ? bq[i] : (i < 2560 ? bk[i - 2048] : bv[i - 2560]);
}

// gather (topk!=null) or direct rows (topk==null) + RMSNorm -> bf16
__global__ void rmsnorm_rows(const float* __restrict__ base, const int* __restrict__ topk,
                             const float* __restrict__ w, bf16* __restrict__ out) {
  const int r = blockIdx.x;
  const float* src;
  if (topk) {
    int t = topk[r];
    src = base + ((int64_t)(r >> 10) * cT + t) * cD;
  } else {
    src = base + (int64_t)r * cD;
  }
  const int tid = threadIdx.x;
  const float4* s4 = (const float4*)src;
  float4 a = s4[tid * 2], b = s4[tid * 2 + 1];
  float ss = a.x * a.x + a.y * a.y + a.z * a.z + a.w * a.w +
             b.x * b.x + b.y * b.y + b.z * b.z + b.w * b.w;
  float tot = blk_reduce<0>(ss);
  float sc = rsqrtf(tot * (1.f / cD) + 1e-6f);
  bf16* o = out + (int64_t)r * cD;
  const int d0 = tid * 8;
  o[d0 + 0] = (bf16)(a.x * sc * w[d0 + 0]);
  o[d0 + 1] = (bf16)(a.y * sc * w[d0 + 1]);
  o[d0 + 2] = (bf16)(a.z * sc * w[d0 + 2]);
  o[d0 + 3] = (bf16)(a.w * sc * w[d0 + 3]);
  o[d0 + 4] = (bf16)(b.x * sc * w[d0 + 4]);
  o[d0 + 5] = (bf16)(b.y * sc * w[d0 + 5]);
  o[d0 + 6] = (bf16)(b.z * sc * w[d0 + 6]);
  o[d0 + 7] = (bf16)(b.w * sc * w[d0 + 7]);
}

__global__ void rope_kernel(bf16* __restrict__ qkv, const float* __restrict__ cosb,
                            const float* __restrict__ sinb, const int* __restrict__ topk) {
  const int r = blockIdx.x;  // b*K + k
  const int b = r >> 10;
  const int t = topk[r];
  const float* cr = cosb + ((int64_t)b * cT + t) * cHD;
  const float* sr = sinb + ((int64_t)b * cT + t) * cHD;
  bf16* rowq = qkv + (int64_t)r * QKVW;
  for (int p = threadIdx.x; p < (cH + cKVH) * 64; p += 256) {
    int hh = p >> 6, d = p & 63;
    bf16* base = (hh < cH) ? (rowq + hh * cHD) : (rowq + cH * cHD + (hh - cH) * cHD);
    float x1 = (float)base[d], x2 = (float)base[d + 64];
    float c1 = cr[d], s1 = sr[d], c2 = cr[d + 64], s2 = sr[d + 64];
    base[d] = (bf16)(x1 * c1 - x2 * s1);
    base[d + 64] = (bf16)(x2 * c2 + x1 * s2);
  }
}

// v-part of qkv -> Vt (B,KVH,HD,K) bf16
__global__ void vtrans(const bf16* __restrict__ qkv, bf16* __restrict__ Vt) {
  __shared__ bf16 t[32][33];
  const int bz = blockIdx.z, b = bz >> 2, kv = bz & 3;
  const int k0 = blockIdx.x * 32, d0 = blockIdx.y * 32;
  for (int rr = threadIdx.y; rr < 32; rr += 8)
    t[rr][threadIdx.x] =
        qkv[(int64_t)(b * cK + k0 + rr) * QKVW + cH * cHD + cKVH * cHD + kv * cHD + d0 + threadIdx.x];
  __syncthreads();
  for (int rr = threadIdx.y; rr < 32; rr += 8)
    Vt[((int64_t)(b * cKVH + kv) * cHD + d0 + rr) * cK + k0 + threadIdx.x] = t[threadIdx.x][rr];
}

}  // namespace

extern "C" void kernel_launch(void* const* d_in, const int* in_sizes, int n_in,
                              void* d_out, int out_size, void* d_ws, size_t ws_size,
                              hipStream_t stream) {
  const float* hidden = (const float*)d_in[0];
  const int* topk = (const int*)d_in[1];
  const float* gating = (const float*)d_in[2];
  const float* cosb = (const float*)d_in[3];
  const float* sinb = (const float*)d_in[4];
  const float* Wq = (const float*)d_in[5];
  const float* bq = (const float*)d_in[6];
  const float* Wk = (const float*)d_in[7];
  const float* bk = (const float*)d_in[8];
  const float* Wv = (const float*)d_in[9];
  const float* bv = (const float*)d_in[10];
  const float* Wo = (const float*)d_in[11];
  const float* wg = (const float*)d_in[12];
  const float* wu = (const float*)d_in[13];
  const float* wd = (const float*)d_in[14];
  const float* ln1 = (const float*)d_in[15];
  const float* ln2 = (const float*)d_in[16];
  float* out = (float*)d_out;
  (void)in_sizes; (void)n_in; (void)out_size; (void)ws_size;

  char* ws = (char*)d_ws;
  size_t off = 0;
  auto alloc = [&](size_t bytes) {
    char* p = ws + off;
    off += (bytes + 255) & ~(size_t)255;
    return p;
  };
  bf16* wt_qkv = (bf16*)alloc((size_t)QKVW * cD * 2);
  bf16* wt_o = (bf16*)alloc((size_t)cD * cD * 2);
  bf16* wt_g = (bf16*)alloc((size_t)cFF * cD * 2);
  bf16* wt_u = (bf16*)alloc((size_t)cFF * cD * 2);
  bf16* wt_d = (bf16*)alloc((size_t)cD * cFF * 2);
  float* bias_cat = (float*)alloc((size_t)QKVW * 4);
  bf16* hbuf = (bf16*)alloc((size_t)cM * cD * 2);
  bf16* qkv = (bf16*)alloc((size_t)cM * QKVW * 2);
  bf16* vt = (bf16*)alloc((size_t)cB * cKVH * cHD * cK * 2);
  bf16* attnout = (bf16*)alloc((size_t)cM * cD * 2);
  float* xbuf = (float*)alloc((size_t)cM * cD * 4);
  bf16* actbuf = (bf16*)alloc((size_t)cM * cFF * 2);

  // d_out = hidden_states (scatter overwrites selected rows later)
  copy_f4<<<2048, 256, 0, stream>>>((const float4*)hidden, (float4*)out,
                                    (int64_t)cB * cT * cD / 4);

  const dim3 tb(32, 8);
  wconv<<<dim3(cD / 32, cD / 32), tb, 0, stream>>>(Wq, wt_qkv, cD, cD, 0, cD);
  wconv<<<dim3(512 / 32, cD / 32), tb, 0, stream>>>(Wk, wt_qkv, cD, 512, 2048, cD);
  wconv<<<dim3(512 / 32, cD / 32), tb, 0, stream>>>(Wv, wt_qkv, cD, 512, 2560, cD);
  wconv<<<dim3(cD / 32, cD / 32), tb, 0, stream>>>(Wo, wt_o, cD, cD, 0, cD);
  wconv<<<dim3(cFF / 32, cD / 32), tb, 0, stream>>>(wg, wt_g, cD, cFF, 0, cD);
  wconv<<<dim3(cFF / 32, cD / 32), tb, 0, stream>>>(wu, wt_u, cD, cFF, 0, cD);
  wconv<<<dim3(cD / 32, cFF / 32), tb, 0, stream>>>(wd, wt_d, cFF, cD, 0, cFF);
  biascat<<<(QKVW + 255) / 256, 256, 0, stream>>>(bq, bk, bv, bias_cat);

  // gather + rmsnorm1
  rmsnorm_rows<<<cM, 256, 0, stream>>>(hidden, topk, ln1, hbuf);
  // qkv projection (+bias)
  gemm256<256, 2, 4, 4, EpiQKV><<<16 * (QKVW / 256), 512, 0, stream>>>(
      hbuf, cD, wt_qkv, cD, cD, 16, EpiQKV{qkv, bias_cat});
  rope_kernel<<<cM, 256, 0, stream>>>(qkv, cosb, sinb, topk);
  vtrans<<<dim3(cK / 32, cHD / 32, cB * cKVH), tb, 0, stream>>>(qkv, vt);

  // fused flash attention (replaces S-GEMM + softmax + PV)
  flash_attn<<<dim3(cK / 64, cH, cB), 256, 0, stream>>>(qkv, vt, attnout);

  // o-proj + gathered residual -> x (fp32)
  gemm256<128, 4, 2, 5, EpiOProj><<<16 * (cD / 128), 512, 0, stream>>>(
      attnout, cD, wt_o, cD, cD, 16, EpiOProj{xbuf, hidden, topk});
  // rmsnorm2
  rmsnorm_rows<<<cM, 256, 0, stream>>>(xbuf, nullptr, ln2, hbuf);
  // gate, then act = silu(gate)*up in place
  gemm256<256, 2, 4, 4, EpiBF16Out><<<16 * (cFF / 256), 512, 0, stream>>>(
      hbuf, cD, wt_g, cD, cD, 16, EpiBF16Out{actbuf, cFF});
  gemm256<256, 2, 4, 4, EpiUp><<<16 * (cFF / 256), 512, 0, stream>>>(
      hbuf, cD, wt_u, cD, cD, 16, EpiUp{actbuf});
  // down + residual + gating + scatter into d_out
  gemm256<128, 4, 2, 5, EpiDown><<<16 * (cD / 128), 512, 0, stream>>>(
      actbuf, cFF, wt_d, cFF, cFF, 16, EpiDown{out, xbuf, hidden, topk, gating});
}

// Round 7
// 868.169 us; speedup vs baseline: 1.4860x; 1.0336x over previous
//
#include <hip/hip_runtime.h>
#include <stdint.h>

typedef __bf16 bf16;
typedef __attribute__((ext_vector_type(8))) __bf16 bf16x8;
typedef __attribute__((ext_vector_type(4))) float f32x4;

namespace {

constexpr int cB = 4, cT = 4096, cD = 2048, cK = 1024, cH = 16, cKVH = 4, cHD = 128, cFF = 8192;
constexpr int cM = cB * cK;                 // 4096 gathered rows
constexpr int QKVW = cH * cHD + 2 * cKVH * cHD; // 3072

__device__ __forceinline__ void load_lds16(const void* g, void* l) {
  __builtin_amdgcn_global_load_lds((const __attribute__((address_space(1))) void*)g,
                                   (__attribute__((address_space(3))) void*)l, 16, 0, 0);
}

template <int N>
__device__ __forceinline__ void waitcnt_vm() {
  if constexpr (N == 0) asm volatile("s_waitcnt vmcnt(0)" ::: "memory");
  else if constexpr (N == 3) asm volatile("s_waitcnt vmcnt(3)" ::: "memory");
  else if constexpr (N == 4) asm volatile("s_waitcnt vmcnt(4)" ::: "memory");
  else if constexpr (N == 6) asm volatile("s_waitcnt vmcnt(6)" ::: "memory");
  else if constexpr (N == 8) asm volatile("s_waitcnt vmcnt(8)" ::: "memory");
  else if constexpr (N == 9) asm volatile("s_waitcnt vmcnt(9)" ::: "memory");
  else if constexpr (N == 12) asm volatile("s_waitcnt vmcnt(12)" ::: "memory");
  else static_assert(N == 0, "unsupported vmcnt literal");
}

// ---------------- block reduce (256 threads = 4 waves) ----------------
template <int OP>  // 0 = sum, 1 = max
__device__ __forceinline__ float blk_reduce(float v) {
  __shared__ float sm[5];
  const int tid = threadIdx.x, lane = tid & 63, wid = tid >> 6;
#pragma unroll
  for (int o = 32; o; o >>= 1) {
    float o2 = __shfl_down(v, o, 64);
    v = OP ? fmaxf(v, o2) : v + o2;
  }
  if (lane == 0) sm[wid] = v;
  __syncthreads();
  if (tid == 0) {
    float r = sm[0];
#pragma unroll
    for (int i = 1; i < 4; ++i) r = OP ? fmaxf(r, sm[i]) : r + sm[i];
    sm[4] = r;
  }
  __syncthreads();
  float r = sm[4];
  __syncthreads();
  return r;
}

// ================= deep-pipelined 256-row MFMA GEMM: C = A * B^T =================
// A: M x Kd row-major (lda), B: N x Kd row-major (ldb). BM=256, BK=32.
// 8 waves (512 thr), WM x WN wave grid, RING-slot LDS ring, counted vmcnt, raw
// barriers, XOR-swizzled LDS (pre-swizzled global src + swizzled ds_read_b128).
// UNROLL=1: prologue D=RING-1 tiles, main waits (D-1)*L; tail = vmcnt(0) + D computes.
// UNROLL=2 (RING=5): two K-steps per barrier. Iter: stage(t+3),stage(t+4),
//   compute(t),compute(t+1), vmcnt(L) [tiles t+2,t+3 landed], barrier. Slots: writes go
//   to (t-2)%5,(t-1)%5, reads from t%5,(t+1)%5 -> disjoint; previous pair's reads are
//   behind the barrier. Bridge: stage(KT-1), vmcnt(0), barrier, 4 straight computes.
template <int BN, int WM, int WN, int RING, int UNROLL, class Epi>
__global__ __launch_bounds__(512, 2)
void gemm256(const bf16* __restrict__ A, int lda,
             const bf16* __restrict__ Bm, int ldb,
             int Kd, int GM, Epi epi) {
  constexpr int BM = 256;
  constexpr int FM = BM / WM / 16;
  constexpr int FN = BN / WN / 16;
  constexpr int ACALLS = 2;          // 256 rows * 64B / (512 thr * 16B)
  constexpr int BCALLS = BN / 128;
  constexpr int L = ACALLS + BCALLS; // vmem instrs per K-tile per thread
  constexpr int D = RING - 1;        // UNROLL=1 prefetch depth
  constexpr int SLOTA = BM * 64;     // bytes per A K-tile (BK=32 -> 64B rows)
  constexpr int SLOTB = BN * 64;
  constexpr int SLOT = SLOTA + SLOTB;
  __shared__ __align__(16) char lds[RING * SLOT];

  const int tid = threadIdx.x;
  const int lane = tid & 63;
  const int wid = tid >> 6;
  const int l15 = lane & 15, lq = lane >> 4;
  const int wr = wid / WN, wc = wid % WN;

  // per-XCD contiguous chunk (nwg % 8 == 0 for all our launches)
  const int nwg = gridDim.x;
  const int xcd = blockIdx.x & 7, loc = blockIdx.x >> 3;
  const int wg = xcd * (nwg >> 3) + loc;
  // grouped mapping: 8 bm fastest, then bn
  const int GN = nwg / GM;
  const int per = 8 * GN;
  const int g = wg / per, r = wg % per;
  const int bm = g * 8 + (r & 7);
  const int bn = r >> 3;

  const bf16* Abase = A + (int64_t)bm * BM * lda;
  const bf16* Bbase = Bm + (int64_t)bn * BN * ldb;

  // staging: LDS linear chunk -> pre-swizzled global source
  const bf16* srcA[ACALLS];
  int dstA[ACALLS];
#pragma unroll
  for (int c2 = 0; c2 < ACALLS; ++c2) {
    const int chunk = c2 * 512 + tid;
    const int row = chunk >> 2, pc = chunk & 3;
    const int lc = pc ^ ((row >> 1) & 3);
    srcA[c2] = Abase + (int64_t)row * lda + lc * 8;
    dstA[c2] = chunk * 16;
  }
  const bf16* srcB[BCALLS];
  int dstB[BCALLS];
#pragma unroll
  for (int c2 = 0; c2 < BCALLS; ++c2) {
    const int chunk = c2 * 512 + tid;
    const int row = chunk >> 2, pc = chunk & 3;
    const int lc = pc ^ ((row >> 1) & 3);
    srcB[c2] = Bbase + (int64_t)row * ldb + lc * 8;
    dstB[c2] = chunk * 16;
  }

  // fragment read offsets (swizzled)
  int offA[FM], offB[FN];
#pragma unroll
  for (int m = 0; m < FM; ++m) {
    const int row = wr * (BM / WM) + m * 16 + l15;
    offA[m] = row * 64 + (lq ^ ((row >> 1) & 3)) * 16;
  }
#pragma unroll
  for (int n = 0; n < FN; ++n) {
    const int row = wc * (BN / WN) + n * 16 + l15;
    offB[n] = SLOTA + row * 64 + (lq ^ ((row >> 1) & 3)) * 16;
  }

  const int KT = Kd >> 5;
  auto stage = [&](int t) {
    char* sb = lds + (size_t)(t % RING) * SLOT;
#pragma unroll
    for (int c2 = 0; c2 < ACALLS; ++c2)
      load_lds16(srcA[c2] + t * 32, sb + dstA[c2]);
#pragma unroll
    for (int c2 = 0; c2 < BCALLS; ++c2)
      load_lds16(srcB[c2] + t * 32, sb + SLOTA + dstB[c2]);
  };
  auto compute = [&](int t, f32x4 (&acc)[FM][FN]) {
    const char* sb = lds + (size_t)(t % RING) * SLOT;
    bf16x8 av[FM], bv[FN];
#pragma unroll
    for (int m = 0; m < FM; ++m) av[m] = *(const bf16x8*)(sb + offA[m]);
#pragma unroll
    for (int n = 0; n < FN; ++n) bv[n] = *(const bf16x8*)(sb + offB[n]);
    __builtin_amdgcn_s_setprio(1);
#pragma unroll
    for (int m = 0; m < FM; ++m)
#pragma unroll
      for (int n = 0; n < FN; ++n)
        acc[m][n] = __builtin_amdgcn_mfma_f32_16x16x32_bf16(av[m], bv[n], acc[m][n], 0, 0, 0);
    __builtin_amdgcn_s_setprio(0);
  };

  f32x4 acc[FM][FN] = {};

  if constexpr (UNROLL == 1) {
#pragma unroll
    for (int i = 0; i < D; ++i) stage(i);
    waitcnt_vm<(D - 1) * L>();
    __builtin_amdgcn_s_barrier();
    __builtin_amdgcn_sched_barrier(0);
    for (int t = 0; t < KT - D; ++t) {
      stage(t + D);
      compute(t, acc);
      waitcnt_vm<(D - 1) * L>();
      __builtin_amdgcn_s_barrier();
      __builtin_amdgcn_sched_barrier(0);
    }
    // tail: all remaining tiles staged; one full drain, then straight computes
    waitcnt_vm<0>();
    __builtin_amdgcn_s_barrier();
    for (int t = KT - D; t < KT; ++t) compute(t, acc);
  } else {
    static_assert(RING == 5 && UNROLL == 2, "pair mode is RING=5");
#pragma unroll
    for (int i = 0; i < 3; ++i) stage(i);
    waitcnt_vm<L>();  // tiles 0,1 landed (tile 2 may be in flight)
    __builtin_amdgcn_s_barrier();
    __builtin_amdgcn_sched_barrier(0);
    int t = 0;
    for (; t <= KT - 6; t += 2) {
      stage(t + 3);
      stage(t + 4);
      compute(t, acc);
      compute(t + 1, acc);
      waitcnt_vm<L>();  // tiles t+2,t+3 landed; t+4 may fly
      __builtin_amdgcn_s_barrier();
      __builtin_amdgcn_sched_barrier(0);
    }
    // t == KT-4; staged through KT-2
    stage(KT - 1);
    waitcnt_vm<0>();
    __builtin_amdgcn_s_barrier();
    compute(KT - 4, acc);
    compute(KT - 3, acc);
    compute(KT - 2, acc);
    compute(KT - 1, acc);
  }

#pragma unroll
  for (int m = 0; m < FM; ++m) {
    const int r0 = bm * BM + wr * (BM / WM) + m * 16 + lq * 4;
#pragma unroll
    for (int n = 0; n < FN; ++n) {
      const int c1 = bn * BN + wc * (BN / WN) + n * 16 + l15;
#pragma unroll
      for (int j = 0; j < 4; ++j) epi(r0 + j, c1, acc[m][n][j]);
    }
  }
}

// ================= fused gate+up GEMM: act = silu(A*Bg^T) * (A*Bu^T) =================
// BM=256, BN=128 (per matrix), 8 waves 4x2, RING=4 (128 KB), D=3, L=4 (A:2,Bg:1,Bu:1),
// W=(D-1)*L=8. Dual accumulators (32 MFMA / 12 ds_read per K-step). Epilogue fuses
// silu(g)*u in-register -> writes act once (kills the 64MB actbuf round-trip).
__global__ __launch_bounds__(512, 2)
void gemm_gateup(const bf16* __restrict__ A, const bf16* __restrict__ Bg,
                 const bf16* __restrict__ Bu, bf16* __restrict__ act) {
  constexpr int BM = 256, BN = 128, WM = 4, WN = 2;
  constexpr int FM = 4, FN = 4;
  constexpr int RING = 4, D = 3, L = 4;
  constexpr int SLOTA = BM * 64, SLOTB = BN * 64;
  constexpr int SLOT = SLOTA + 2 * SLOTB;  // 32 KB
  __shared__ __align__(16) char lds[RING * SLOT];

  const int tid = threadIdx.x;
  const int lane = tid & 63;
  const int wid = tid >> 6;
  const int l15 = lane & 15, lq = lane >> 4;
  const int wr = wid / WN, wc = wid % WN;

  const int nwg = gridDim.x;               // 1024
  const int xcd = blockIdx.x & 7, loc = blockIdx.x >> 3;
  const int wg = xcd * (nwg >> 3) + loc;
  const int GM = 16, GN = nwg / GM;        // 64
  const int per = 8 * GN;
  const int g = wg / per, r = wg % per;
  const int bm = g * 8 + (r & 7);
  const int bn = r >> 3;

  const bf16* Abase = A + (int64_t)bm * BM * cD;
  const bf16* Gbase = Bg + (int64_t)bn * BN * cD;
  const bf16* Ubase = Bu + (int64_t)bn * BN * cD;

  const bf16* srcA[2];
  int dstA[2];
#pragma unroll
  for (int c2 = 0; c2 < 2; ++c2) {
    const int chunk = c2 * 512 + tid;
    const int row = chunk >> 2, pc = chunk & 3;
    const int lc = pc ^ ((row >> 1) & 3);
    srcA[c2] = Abase + (int64_t)row * cD + lc * 8;
    dstA[c2] = chunk * 16;
  }
  const int brow = tid >> 2, bpc = tid & 3;
  const int blc = bpc ^ ((brow >> 1) & 3);
  const bf16* srcG = Gbase + (int64_t)brow * cD + blc * 8;
  const bf16* srcU = Ubase + (int64_t)brow * cD + blc * 8;
  const int dstBo = tid * 16;

  int offA[FM], offB[FN];
#pragma unroll
  for (int m = 0; m < FM; ++m) {
    const int row = wr * 64 + m * 16 + l15;
    offA[m] = row * 64 + (lq ^ ((row >> 1) & 3)) * 16;
  }
#pragma unroll
  for (int n = 0; n < FN; ++n) {
    const int row = wc * 64 + n * 16 + l15;
    offB[n] = row * 64 + (lq ^ ((row >> 1) & 3)) * 16;
  }

  const int KT = cD >> 5;  // 64
  auto stage = [&](int t) {
    char* sb = lds + (size_t)(t % RING) * SLOT;
#pragma unroll
    for (int c2 = 0; c2 < 2; ++c2) load_lds16(srcA[c2] + t * 32, sb + dstA[c2]);
    load_lds16(srcG + t * 32, sb + SLOTA + dstBo);
    load_lds16(srcU + t * 32, sb + SLOTA + SLOTB + dstBo);
  };

  f32x4 accg[FM][FN] = {}, accu[FM][FN] = {};

  auto compute = [&](int t) {
    const char* sb = lds + (size_t)(t % RING) * SLOT;
    bf16x8 av[FM], gv[FN], uv[FN];
#pragma unroll
    for (int m = 0; m < FM; ++m) av[m] = *(const bf16x8*)(sb + offA[m]);
#pragma unroll
    for (int n = 0; n < FN; ++n) gv[n] = *(const bf16x8*)(sb + SLOTA + offB[n]);
#pragma unroll
    for (int n = 0; n < FN; ++n) uv[n] = *(const bf16x8*)(sb + SLOTA + SLOTB + offB[n]);
    __builtin_amdgcn_s_setprio(1);
#pragma unroll
    for (int m = 0; m < FM; ++m)
#pragma unroll
      for (int n = 0; n < FN; ++n) {
        accg[m][n] = __builtin_amdgcn_mfma_f32_16x16x32_bf16(av[m], gv[n], accg[m][n], 0, 0, 0);
        accu[m][n] = __builtin_amdgcn_mfma_f32_16x16x32_bf16(av[m], uv[n], accu[m][n], 0, 0, 0);
      }
    __builtin_amdgcn_s_setprio(0);
  };

#pragma unroll
  for (int i = 0; i < D; ++i) stage(i);
  waitcnt_vm<(D - 1) * L>();
  __builtin_amdgcn_s_barrier();
  __builtin_amdgcn_sched_barrier(0);
  for (int t = 0; t < KT - D; ++t) {
    stage(t + D);
    compute(t);
    waitcnt_vm<(D - 1) * L>();
    __builtin_amdgcn_s_barrier();
    __builtin_amdgcn_sched_barrier(0);
  }
  waitcnt_vm<0>();
  __builtin_amdgcn_s_barrier();
  for (int t = KT - D; t < KT; ++t) compute(t);

#pragma unroll
  for (int m = 0; m < FM; ++m) {
    const int r0 = bm * BM + wr * 64 + m * 16 + lq * 4;
#pragma unroll
    for (int n = 0; n < FN; ++n) {
      const int c1 = bn * BN + wc * 64 + n * 16 + l15;
#pragma unroll
      for (int j = 0; j < 4; ++j) {
        float gvv = accg[m][n][j];
        float s = gvv / (1.f + __expf(-gvv));
        act[(int64_t)(r0 + j) * cFF + c1] = (bf16)(s * accu[m][n][j]);
      }
    }
  }
}

// ---------------- epilogues ----------------
struct EpiQKV {
  bf16* out; const float* bias;
  __device__ void operator()(int r, int c, float v) const {
    out[(int64_t)r * QKVW + c] = (bf16)(v + bias[c]);
  }
};
struct EpiOProj {
  float* x; const float* hidden; const int* topk;
  __device__ void operator()(int r, int c, float v) const {
    int b = r >> 10;
    int t = topk[r];
    x[(int64_t)r * cD + c] = v + hidden[((int64_t)b * cT + t) * cD + c];
  }
};
struct EpiDown {  // x2 = x + acc; upd = sel + (x2-sel)*gate; scatter to d_out
  float* out; const float* x; const float* hidden; const int* topk; const float* gating;
  __device__ void operator()(int r, int c, float v) const {
    int b = r >> 10;
    int t = topk[r];
    float x2 = v + x[(int64_t)r * cD + c];
    int64_t ho = ((int64_t)b * cT + t) * cD + c;
    float sel = hidden[ho];
    out[ho] = sel + (x2 - sel) * gating[r];
  }
};

// ================= fused flash attention =================
// grid (16 qtiles of 64 rows, 16 heads, 4 batches), 256 thr = 4 waves.
// Each wave owns 16 FULL rows x all 128 kv-cols; shfl_xor over l15 = exact row reduce.
// LDS: sK 32K (Q staged here first) | sP 16K | sV 32K = 80 KB -> 2 blocks/CU.
// All LDS tiles XOR-swizzled (16B chunk ^ row&15) via pre-swizzled global src.
__global__ __launch_bounds__(256, 2) void flash_attn(const bf16* __restrict__ qkv,
                                                     const bf16* __restrict__ vt,
                                                     bf16* __restrict__ outb) {
  constexpr int QB = 64, KVB = 128;
  __shared__ __align__(16) char lds[81920];
  char* sK = lds;            // 32 KB (also Q staging)
  char* sP = lds + 32768;    // 16 KB
  char* sV = lds + 49152;    // 32 KB

  const int qt = blockIdx.x, h = blockIdx.y, b = blockIdx.z;
  const int kvh = h >> 2;
  const int qlo = qt * QB;
  const int tid = threadIdx.x, lane = tid & 63, wid = tid >> 6;
  const int l15 = lane & 15, lq = lane >> 4;
  const int wid16 = wid * 16;  // this wave's 16-row block

  const bf16* qbase = qkv + (int64_t)(b * cK + qlo) * QKVW + h * cHD;
  const bf16* kbase = qkv + (int64_t)(b * cK) * QKVW + cH * cHD + kvh * cHD;
  const bf16* vtbase = vt + (int64_t)(b * cKVH + kvh) * cHD * cK;

  // ---- stage Q (64 rows x 256B) into sK region, read frags to regs ----
#pragma unroll
  for (int c2 = 0; c2 < 4; ++c2) {
    int chunk = c2 * 256 + tid;
    int row = chunk >> 4, c16 = chunk & 15;
    load_lds16(qbase + (int64_t)row * QKVW + (c16 ^ (row & 15)) * 8, sK + chunk * 16);
  }
  __syncthreads();
  bf16x8 qf[4];
  {
    const int row = wid16 + l15;
#pragma unroll
    for (int kt = 0; kt < 4; ++kt)
      qf[kt] = *(const bf16x8*)(sK + row * 256 + (((kt * 4 + lq) ^ (row & 15)) * 16));
  }
  __syncthreads();  // all Q reads complete before K staging overwrites sK

  f32x4 oacc[8] = {};
  float m_run[4], l_run[4];
#pragma unroll
  for (int j = 0; j < 4; ++j) { m_run[j] = -3.0e38f; l_run[j] = 0.f; }

  const int jmax = (qlo + QB - 1) >> 7;
  const float sl2e = 0.08838834764831845f * 1.44269504088896f;  // scale * log2(e)

  for (int jj = 0; jj <= jmax; ++jj) {
    // stage K tile (128 rows x 256B) and Vt tile (128 d-rows x 256B)
#pragma unroll
    for (int c2 = 0; c2 < 8; ++c2) {
      int chunk = c2 * 256 + tid;
      int row = chunk >> 4, c16 = chunk & 15;
      int cs = (c16 ^ (row & 15)) * 8;
      load_lds16(kbase + (int64_t)(jj * KVB + row) * QKVW + cs, sK + chunk * 16);
      load_lds16(vtbase + (int64_t)row * cK + jj * KVB + cs, sV + chunk * 16);
    }
    __syncthreads();

    // S = Q K^T : rows = this wave's 16 q-rows, cols = all 128 kv of this tile
    f32x4 sacc[8] = {};
#pragma unroll
    for (int kt = 0; kt < 4; ++kt) {
      bf16x8 bv[8];
#pragma unroll
      for (int n = 0; n < 8; ++n) {
        int rk = n * 16 + l15;
        bv[n] = *(const bf16x8*)(sK + rk * 256 + (((kt * 4 + lq) ^ (rk & 15)) * 16));
      }
#pragma unroll
      for (int n = 0; n < 8; ++n)
        sacc[n] = __builtin_amdgcn_mfma_f32_16x16x32_bf16(qf[kt], bv[n], sacc[n], 0, 0, 0);
    }

    // causal mask on diagonal tile
    if (jj == jmax) {
#pragma unroll
      for (int n = 0; n < 8; ++n)
#pragma unroll
        for (int j = 0; j < 4; ++j) {
          int qrow = qlo + wid16 + lq * 4 + j;
          int kcol = jj * KVB + n * 16 + l15;
          if (kcol > qrow) sacc[n][j] = -3.0e38f;
        }
    }

    // online softmax: lane owns rows (lq*4+j); full row = 8 n-frags x 16 l15 lanes
#pragma unroll
    for (int j = 0; j < 4; ++j) {
      float mx = sacc[0][j];
#pragma unroll
      for (int n = 1; n < 8; ++n) mx = fmaxf(mx, sacc[n][j]);
#pragma unroll
      for (int off = 1; off < 16; off <<= 1) mx = fmaxf(mx, __shfl_xor(mx, off, 64));
      float mnew = fmaxf(m_run[j], mx);
      float corr = exp2f((m_run[j] - mnew) * sl2e);
      m_run[j] = mnew;
      float ps = 0.f;
#pragma unroll
      for (int n = 0; n < 8; ++n) {
        float p = exp2f((sacc[n][j] - mnew) * sl2e);
        sacc[n][j] = p;
        ps += p;
      }
#pragma unroll
      for (int off = 1; off < 16; off <<= 1) ps += __shfl_xor(ps, off, 64);
      l_run[j] = l_run[j] * corr + ps;
#pragma unroll
      for (int n = 0; n < 8; ++n) oacc[n][j] *= corr;
    }

    // P -> LDS (bf16, swizzled); same wave writes and reads its own 16 rows
#pragma unroll
    for (int n = 0; n < 8; ++n)
#pragma unroll
      for (int j = 0; j < 4; ++j) {
        int row = wid16 + lq * 4 + j;
        int col = n * 16 + l15;
        int c16 = (col >> 3) ^ (row & 15);
        *(bf16*)(sP + row * 256 + c16 * 16 + (col & 7) * 2) = (bf16)sacc[n][j];
      }
    __syncthreads();

    // O += P @ Vt^T  (A = P own rows, B = Vt d-rows)
#pragma unroll
    for (int kt = 0; kt < 4; ++kt) {
      const int prow = wid16 + l15;
      bf16x8 av = *(const bf16x8*)(sP + prow * 256 + (((kt * 4 + lq) ^ (prow & 15)) * 16));
      bf16x8 bv[8];
#pragma unroll
      for (int n = 0; n < 8; ++n) {
        int rd = n * 16 + l15;
        bv[n] = *(const bf16x8*)(sV + rd * 256 + (((kt * 4 + lq) ^ (rd & 15)) * 16));
      }
#pragma unroll
      for (int n = 0; n < 8; ++n)
        oacc[n] = __builtin_amdgcn_mfma_f32_16x16x32_bf16(av, bv[n], oacc[n], 0, 0, 0);
    }
    __syncthreads();  // PV reads of sP/sV done before next stage overwrites
  }

  // O / l -> attnout
#pragma unroll
  for (int j = 0; j < 4; ++j) {
    int row = qlo + wid16 + lq * 4 + j;
    float inv = 1.f / l_run[j];
#pragma unroll
    for (int n = 0; n < 8; ++n) {
      int col = h * cHD + n * 16 + l15;
      outb[((int64_t)b * cK + row) * cD + col] = (bf16)(oacc[n][j] * inv);
    }
  }
}

// ---------------- elementwise / staging kernels ----------------
__global__ void copy_f4(const float4* __restrict__ s, float4* __restrict__ d, int64_t n) {
  int64_t i = (int64_t)blockIdx.x * blockDim.x + threadIdx.x;
  const int64_t st = (int64_t)gridDim.x * blockDim.x;
  for (; i < n; i += st) d[i] = s[i];
}

// fp32 (R,C) -> bf16 (C,R) with column offset into a concat buffer
__global__ void wconv(const float* __restrict__ src, bf16* __restrict__ dst,
                      int R, int C, int coff, int ldd) {
  __shared__ float t[32][33];
  const int c0 = blockIdx.x * 32, r0 = blockIdx.y * 32;
  for (int rr = threadIdx.y; rr < 32; rr += 8)
    t[rr][threadIdx.x] = src[(int64_t)(r0 + rr) * C + c0 + threadIdx.x];
  __syncthreads();
  for (int rr = threadIdx.y; rr < 32; rr += 8)
    dst[(int64_t)(c0 + rr + coff) * ldd + r0 + threadIdx.x] = (bf16)t[threadIdx.x][rr];
}

__global__ void biascat(const float* __restrict__ bq, const float* __restrict__ bk,
                        const float* __restrict__ bv, float* __restrict__ o) {
  int i = blockIdx.x * 256 + threadIdx.x;
  if (i < QKVW) o[i] = (i < 2048) ? bq[i] : (i < 2560 ? bk[i - 2048] : bv[i - 2560]);
}

// gather (topk!=null) or direct rows (topk==null) + RMSNorm -> bf16
__global__ void rmsnorm_rows(const float* __restrict__ base, const int* __restrict__ topk,
                             const float* __restrict__ w, bf16* __restrict__ out) {
  const int r = blockIdx.x;
  const float* src;
  if (topk) {
    int t = topk[r];
    src = base + ((int64_t)(r >> 10) * cT + t) * cD;
  } else {
    src = base + (int64_t)r * cD;
  }
  const int tid = threadIdx.x;
  const float4* s4 = (const float4*)src;
  float4 a = s4[tid * 2], b = s4[tid * 2 + 1];
  float ss = a.x * a.x + a.y * a.y + a.z * a.z + a.w * a.w +
             b.x * b.x + b.y * b.y + b.z * b.z + b.w * b.w;
  float tot = blk_reduce<0>(ss);
  float sc = rsqrtf(tot * (1.f / cD) + 1e-6f);
  bf16* o = out + (int64_t)r * cD;
  const int d0 = tid * 8;
  o[d0 + 0] = (bf16)(a.x * sc * w[d0 + 0]);
  o[d0 + 1] = (bf16)(a.y * sc * w[d0 + 1]);
  o[d0 + 2] = (bf16)(a.z * sc * w[d0 + 2]);
  o[d0 + 3] = (bf16)(a.w * sc * w[d0 + 3]);
  o[d0 + 4] = (bf16)(b.x * sc * w[d0 + 4]);
  o[d0 + 5] = (bf16)(b.y * sc * w[d0 + 5]);
  o[d0 + 6] = (bf16)(b.z * sc * w[d0 + 6]);
  o[d0 + 7] = (bf16)(b.w * sc * w[d0 + 7]);
}

__global__ void rope_kernel(bf16* __restrict__ qkv, const float* __restrict__ cosb,
                            const float* __restrict__ sinb, const int* __restrict__ topk) {
  const int r = blockIdx.x;  // b*K + k
  const int b = r >> 10;
  const int t = topk[r];
  const float* cr = cosb + ((int64_t)b * cT + t) * cHD;
  const float* sr = sinb + ((int64_t)b * cT + t) * cHD;
  bf16* rowq = qkv + (int64_t)r * QKVW;
  for (int p = threadIdx.x; p < (cH + cKVH) * 64; p += 256) {
    int hh = p >> 6, d = p & 63;
    bf16* base = (hh < cH) ? (rowq + hh * cHD) : (rowq + cH * cHD + (hh - cH) * cHD);
    float x1 = (float)base[d], x2 = (float)base[d + 64];
    float c1 = cr[d], s1 = sr[d], c2 = cr[d + 64], s2 = sr[d + 64];
    base[d] = (bf16)(x1 * c1 - x2 * s1);
    base[d + 64] = (bf16)(x2 * c2 + x1 * s2);
  }
}

// v-part of qkv -> Vt (B,KVH,HD,K) bf16
__global__ void vtrans(const bf16* __restrict__ qkv, bf16* __restrict__ Vt) {
  __shared__ bf16 t[32][33];
  const int bz = blockIdx.z, b = bz >> 2, kv = bz & 3;
  const int k0 = blockIdx.x * 32, d0 = blockIdx.y * 32;
  for (int rr = threadIdx.y; rr < 32; rr += 8)
    t[rr][threadIdx.x] =
        qkv[(int64_t)(b * cK + k0 + rr) * QKVW + cH * cHD + cKVH * cHD + kv * cHD + d0 + threadIdx.x];
  __syncthreads();
  for (int rr = threadIdx.y; rr < 32; rr += 8)
    Vt[((int64_t)(b * cKVH + kv) * cHD + d0 + rr) * cK + k0 + threadIdx.x] = t[threadIdx.x][rr];
}

}  // namespace

extern "C" void kernel_launch(void* const* d_in, const int* in_sizes, int n_in,
                              void* d_out, int out_size, void* d_ws, size_t ws_size,
                              hipStream_t stream) {
  const float* hidden = (const float*)d_in[0];
  const int* topk = (const int*)d_in[1];
  const float* gating = (const float*)d_in[2];
  const float* cosb = (const float*)d_in[3];
  const float* sinb = (const float*)d_in[4];
  const float* Wq = (const float*)d_in[5];
  const float* bq = (const float*)d_in[6];
  const float* Wk = (const float*)d_in[7];
  const float* bk = (const float*)d_in[8];
  const float* Wv = (const float*)d_in[9];
  const float* bv = (const float*)d_in[10];
  const float* Wo = (const float*)d_in[11];
  const float* wg = (const float*)d_in[12];
  const float* wu = (const float*)d_in[13];
  const float* wd = (const float*)d_in[14];
  const float* ln1 = (const float*)d_in[15];
  const float* ln2 = (const float*)d_in[16];
  float* out = (float*)d_out;
  (void)in_sizes; (void)n_in; (void)out_size; (void)ws_size;

  char* ws = (char*)d_ws;
  size_t off = 0;
  auto alloc = [&](size_t bytes) {
    char* p = ws + off;
    off += (bytes + 255) & ~(size_t)255;
    return p;
  };
  bf16* wt_qkv = (bf16*)alloc((size_t)QKVW * cD * 2);
  bf16* wt_o = (bf16*)alloc((size_t)cD * cD * 2);
  bf16* wt_g = (bf16*)alloc((size_t)cFF * cD * 2);
  bf16* wt_u = (bf16*)alloc((size_t)cFF * cD * 2);
  bf16* wt_d = (bf16*)alloc((size_t)cD * cFF * 2);
  float* bias_cat = (float*)alloc((size_t)QKVW * 4);
  bf16* hbuf = (bf16*)alloc((size_t)cM * cD * 2);
  bf16* qkv = (bf16*)alloc((size_t)cM * QKVW * 2);
  bf16* vt = (bf16*)alloc((size_t)cB * cKVH * cHD * cK * 2);
  bf16* attnout = (bf16*)alloc((size_t)cM * cD * 2);
  float* xbuf = (float*)alloc((size_t)cM * cD * 4);
  bf16* actbuf = (bf16*)alloc((size_t)cM * cFF * 2);

  // d_out = hidden_states (scatter overwrites selected rows later)
  copy_f4<<<2048, 256, 0, stream>>>((const float4*)hidden, (float4*)out,
                                    (int64_t)cB * cT * cD / 4);

  const dim3 tb(32, 8);
  wconv<<<dim3(cD / 32, cD / 32), tb, 0, stream>>>(Wq, wt_qkv, cD, cD, 0, cD);
  wconv<<<dim3(512 / 32, cD / 32), tb, 0, stream>>>(Wk, wt_qkv, cD, 512, 2048, cD);
  wconv<<<dim3(512 / 32, cD / 32), tb, 0, stream>>>(Wv, wt_qkv, cD, 512, 2560, cD);
  wconv<<<dim3(cD / 32, cD / 32), tb, 0, stream>>>(Wo, wt_o, cD, cD, 0, cD);
  wconv<<<dim3(cFF / 32, cD / 32), tb, 0, stream>>>(wg, wt_g, cD, cFF, 0, cD);
  wconv<<<dim3(cFF / 32, cD / 32), tb, 0, stream>>>(wu, wt_u, cD, cFF, 0, cD);
  wconv<<<dim3(cD / 32, cFF / 32), tb, 0, stream>>>(wd, wt_d, cFF, cD, 0, cFF);
  biascat<<<(QKVW + 255) / 256, 256, 0, stream>>>(bq, bk, bv, bias_cat);

  // gather + rmsnorm1
  rmsnorm_rows<<<cM, 256, 0, stream>>>(hidden, topk, ln1, hbuf);
  // qkv projection (+bias)
  gemm256<256, 2, 4, 4, 1, EpiQKV><<<16 * (QKVW / 256), 512, 0, stream>>>(
      hbuf, cD, wt_qkv, cD, cD, 16, EpiQKV{qkv, bias_cat});
  rope_kernel<<<cM, 256, 0, stream>>>(qkv, cosb, sinb, topk);
  vtrans<<<dim3(cK / 32, cHD / 32, cB * cKVH), tb, 0, stream>>>(qkv, vt);

  // fused flash attention (replaces S-GEMM + softmax + PV)
  flash_attn<<<dim3(cK / 64, cH, cB), 256, 0, stream>>>(qkv, vt, attnout);

  // o-proj + gathered residual -> x (fp32)   [pair-mode pipeline]
  gemm256<128, 4, 2, 5, 2, EpiOProj><<<16 * (cD / 128), 512, 0, stream>>>(
      attnout, cD, wt_o, cD, cD, 16, EpiOProj{xbuf, hidden, topk});
  // rmsnorm2
  rmsnorm_rows<<<cM, 256, 0, stream>>>(xbuf, nullptr, ln2, hbuf);
  // fused gate+up -> act = silu(gate)*up (single pass, no actbuf round-trip)
  gemm_gateup<<<16 * (cFF / 128), 512, 0, stream>>>(hbuf, wt_g, wt_u, actbuf);
  // down + residual + gating + scatter into d_out   [pair-mode pipeline]
  gemm256<128, 4, 2, 5, 2, EpiDown><<<16 * (cD / 128), 512, 0, stream>>>(
      actbuf, cFF, wt_d, cFF, cFF, 16, EpiDown{out, xbuf, hidden, topk, gating});
}